// Round 3
// baseline (90.193 us; speedup 1.0000x reference)
//
#include <hip/hip_runtime.h>

#define BB 4
#define SS 4096
#define DDIM 1024
#define KDIM 64
#define CHUNK 64
#define NCHUNK 64          // SS / CHUNK
#define TCHUNK 256         // BB * NCHUNK
#define MROWS 16384        // BB * SS

typedef short short8v __attribute__((ext_vector_type(8)));
typedef float f32x4 __attribute__((ext_vector_type(4)));
#define MFMA16 __builtin_amdgcn_mfma_f32_16x16x32_bf16

__device__ __forceinline__ ushort f2bf(float f) {
    // round-to-nearest-even f32 -> bf16
    uint u = __float_as_uint(f);
    u += 0x7FFFu + ((u >> 16) & 1u);
    return (ushort)(u >> 16);
}

__device__ __forceinline__ void ld4(float* d, const float* p) {
    float4 v = *(const float4*)p;
    d[0] = v.x; d[1] = v.y; d[2] = v.z; d[3] = v.w;
}

// XOR swizzle used by k_intra's Kf tile
__device__ __forceinline__ int swz(int r, int c) {
    return r * 64 + ((((c >> 2) ^ ((r >> 2) & 7)) << 2) | (c & 3));
}

// ---------------- Kernel 0: weight conversion f32 -> bf16 ----------------
__global__ __launch_bounds__(256) void k_wconv(
    const float* __restrict__ Wq, const float* __restrict__ Wk,
    const float* __restrict__ Wv, const float* __restrict__ Wo,
    ushort* __restrict__ Wh, ushort* __restrict__ Woh)
{
    const int b = blockIdx.x, t = threadIdx.x;
    if (b < 192) {
        const float* src = (b < 64) ? (Wq + (size_t)b * DDIM)
                         : (b < 128) ? (Wk + (size_t)(b - 64) * DDIM)
                                     : (Wv + (size_t)(b - 128) * DDIM);
#pragma unroll
        for (int i = 0; i < 4; ++i)
            Wh[(size_t)b * DDIM + i * 256 + t] = f2bf(src[i * 256 + t]);
    } else {
        const int off = (b - 192) * 256 + t;
        Woh[off] = f2bf(Wo[off]);
    }
}

// ---------------- Kernel 1: fused QKV projection (bf16 MFMA, barrier-free loop) ----------------
// C[16384,192] = x @ [Wq;Wk;Wv]^T ; cols 0..127 get elu()+1.
// BM=32, BN=192; grid=512 (2 blocks/CU), 4 waves, wave tile 32x48.
// x staged ONCE into LDS as bf16 fragments (64KB, all 32 K-steps), one barrier.
// W fragments loaded global->reg (L2-resident), depth-4 prefetch. No loop barriers.
__global__ __launch_bounds__(256) void k_proj(
    const float* __restrict__ x, const ushort* __restrict__ Wh,
    float* __restrict__ Q, float* __restrict__ Kf, float* __restrict__ V)
{
    // frag slot (rf, ks): 64 lanes x 8 bf16; lane l holds
    // x[row0 + rf*16 + (l&15)][ks*32 + ((l>>4)&3)*8 + 0..7]
    __shared__ ushort xs[2 * 32 * 64 * 8];   // 64 KB
    const int t = threadIdx.x;
    const int row0 = blockIdx.x * 32;

    // ---- stage x (32 rows x 1024 k) as bf16 frags; one barrier ----
    {
        const int r = t >> 3;            // 0..31
        const int rf = r >> 4, rl = r & 15;
        const int kbase = (t & 7) * 128;
        const float* xrow = &x[(size_t)(row0 + r) * DDIM + kbase];
#pragma unroll
        for (int kc = 0; kc < 128; kc += 8) {
            float4 u0 = *(const float4*)(xrow + kc);
            float4 u1 = *(const float4*)(xrow + kc + 4);
            short8v h;
            h[0] = (short)f2bf(u0.x); h[1] = (short)f2bf(u0.y);
            h[2] = (short)f2bf(u0.z); h[3] = (short)f2bf(u0.w);
            h[4] = (short)f2bf(u1.x); h[5] = (short)f2bf(u1.y);
            h[6] = (short)f2bf(u1.z); h[7] = (short)f2bf(u1.w);
            const int k = kbase + kc;
            const int slot = ((rf * 32 + (k >> 5)) * 64) + (rl | (((k >> 3) & 3) << 4));
            *(short8v*)&xs[slot * 8] = h;
        }
    }
    __syncthreads();

    // ---- main loop: 32 K-steps, W direct global->reg, depth-4 prefetch ----
    const int w = t >> 6, l = t & 63;
    const ushort* wp0 = Wh + (size_t)(w * 48 + (l & 15)) * DDIM + ((l >> 4) & 3) * 8;
    const ushort* wp1 = wp0 + (size_t)16 * DDIM;
    const ushort* wp2 = wp0 + (size_t)32 * DDIM;

    f32x4 acc[2][3];
#pragma unroll
    for (int r = 0; r < 2; ++r)
#pragma unroll
        for (int c = 0; c < 3; ++c) acc[r][c] = (f32x4){0.f, 0.f, 0.f, 0.f};

    short8v bw[2][4][3];
#pragma unroll
    for (int s = 0; s < 4; ++s) {
        bw[0][s][0] = *(const short8v*)(wp0 + s * 32);
        bw[0][s][1] = *(const short8v*)(wp1 + s * 32);
        bw[0][s][2] = *(const short8v*)(wp2 + s * 32);
    }
#pragma unroll
    for (int kb = 0; kb < 8; ++kb) {
        const int cur = kb & 1, nxt = cur ^ 1;
        if (kb < 7) {
#pragma unroll
            for (int s = 0; s < 4; ++s) {
                const int ks = (kb + 1) * 4 + s;
                bw[nxt][s][0] = *(const short8v*)(wp0 + ks * 32);
                bw[nxt][s][1] = *(const short8v*)(wp1 + ks * 32);
                bw[nxt][s][2] = *(const short8v*)(wp2 + ks * 32);
            }
        }
#pragma unroll
        for (int s = 0; s < 4; ++s) {
            const int ks = kb * 4 + s;
            short8v a0 = *(const short8v*)&xs[(ks * 64 + l) * 8];
            short8v a1 = *(const short8v*)&xs[((32 + ks) * 64 + l) * 8];
#pragma unroll
            for (int c = 0; c < 3; ++c) {
                acc[0][c] = MFMA16(a0, bw[cur][s][c], acc[0][c], 0, 0, 0);
                acc[1][c] = MFMA16(a1, bw[cur][s][c], acc[1][c], 0, 0, 0);
            }
        }
    }

    // ---- epilogue: C/D layout col=l&15, row=(l>>4)*4+q ----
#pragma unroll
    for (int rf = 0; rf < 2; ++rf) {
#pragma unroll
        for (int c = 0; c < 3; ++c) {
            const int col = w * 48 + c * 16 + (l & 15);
#pragma unroll
            for (int q = 0; q < 4; ++q) {
                const int row = row0 + rf * 16 + ((l >> 4) << 2) + q;
                float v = acc[rf][c][q];
                if (col < 128) v = (v > 0.f) ? v + 1.f : __expf(v);  // elu+1
                if (col < 64)       Q[(size_t)row * KDIM + col] = v;
                else if (col < 128) Kf[(size_t)row * KDIM + (col - 64)] = v;
                else                V[(size_t)row * KDIM + (col - 128)] = v;
            }
        }
    }
}

// ---------------- Kernel 2: per-chunk KV summary ----------------
__global__ __launch_bounds__(256) void k_chunksum(
    const float* __restrict__ Kf, const float* __restrict__ V,
    float* __restrict__ KVc, float* __restrict__ Ksc)
{
    __shared__ float ks[64][68];
    __shared__ float vs[64][68];
    const int g = blockIdx.x;
    const int t = threadIdx.x;
#pragma unroll
    for (int i = 0; i < 4; ++i) {
        const int f4 = i * 256 + t;
        const int r = f4 >> 4;
        const int kq = (f4 & 15) << 2;
        const size_t gi = ((size_t)g * 64 + r) * KDIM + kq;
        *(float4*)&ks[r][kq] = *(const float4*)&Kf[gi];
        *(float4*)&vs[r][kq] = *(const float4*)&V[gi];
    }
    __syncthreads();
    const int tx = t & 15, ty = t >> 4;
    float acc[4][4];
#pragma unroll
    for (int i = 0; i < 4; ++i)
#pragma unroll
        for (int m = 0; m < 4; ++m) acc[i][m] = 0.f;
    for (int j = 0; j < 64; ++j) {
        float ka[4], va[4];
        ld4(ka, &ks[j][ty * 4]);
        ld4(va, &vs[j][tx * 4]);
#pragma unroll
        for (int i = 0; i < 4; ++i)
#pragma unroll
            for (int m = 0; m < 4; ++m)
                acc[i][m] = fmaf(ka[i], va[m], acc[i][m]);
    }
#pragma unroll
    for (int i = 0; i < 4; ++i)
#pragma unroll
        for (int m = 0; m < 4; ++m)
            KVc[(size_t)g * 4096 + (size_t)(ty * 4 + i) * 64 + tx * 4 + m] = acc[i][m];
    if (t < 64) {
        float s = 0.f;
        for (int j = 0; j < 64; ++j) s += ks[j][t];
        Ksc[(size_t)g * KDIM + t] = s;
    }
}

// ---------------- Kernel 3: exclusive prefix over chunks (batched loads) ----------------
__global__ void k_scan(const float* __restrict__ KVc, const float* __restrict__ Ksc,
                       float* __restrict__ Sst, float* __restrict__ Kss)
{
    const int b = blockIdx.x / 65;
    const int r = blockIdx.x % 65;
    const int t = threadIdx.x;
    float acc = 0.f;
    if (r < 64) {
        const int e = r * 64 + t;
        for (int c0 = 0; c0 < NCHUNK; c0 += 8) {
            float v[8];
#pragma unroll
            for (int i = 0; i < 8; ++i)
                v[i] = KVc[((size_t)(b * NCHUNK + c0 + i)) * 4096 + e];
#pragma unroll
            for (int i = 0; i < 8; ++i) {
                Sst[((size_t)(b * NCHUNK + c0 + i)) * 4096 + e] = acc;
                acc += v[i];
            }
        }
    } else {
        for (int c0 = 0; c0 < NCHUNK; c0 += 8) {
            float v[8];
#pragma unroll
            for (int i = 0; i < 8; ++i)
                v[i] = Ksc[((size_t)(b * NCHUNK + c0 + i)) * KDIM + t];
#pragma unroll
            for (int i = 0; i < 8; ++i) {
                Kss[((size_t)(b * NCHUNK + c0 + i)) * KDIM + t] = acc;
                acc += v[i];
            }
        }
    }
}

// ---------------- Kernel 4: intra-chunk attention + state apply ----------------
__global__ __launch_bounds__(256) void k_intra(
    const float* __restrict__ Q, const float* __restrict__ Kf,
    const float* __restrict__ V, const float* __restrict__ Sst,
    const float* __restrict__ Kss, ushort* __restrict__ Ob)
{
    __shared__ float qs[64][68];
    __shared__ float kT[64 * 64];
    __shared__ float vs[64][68];
    __shared__ float ss[64][68];
    __shared__ float am[64][68];
    __shared__ float denl[64];
    __shared__ float ksuml[64];
    const int g = blockIdx.x;
    const int t = threadIdx.x;
    const int tx = t & 15, ty = t >> 4;
#pragma unroll
    for (int i = 0; i < 4; ++i) {
        const int f4 = i * 256 + t;
        const int r = f4 >> 4;
        const int kq = (f4 & 15) << 2;
        const size_t gi = ((size_t)g * 64 + r) * KDIM + kq;
        *(float4*)&qs[r][kq] = *(const float4*)&Q[gi];
        *(float4*)&kT[swz(r, kq)] = *(const float4*)&Kf[gi];
        *(float4*)&vs[r][kq] = *(const float4*)&V[gi];
        *(float4*)&ss[r][kq] = *(const float4*)&Sst[(size_t)g * 4096 + (size_t)f4 * 4];
    }
    if (t < 64) ksuml[t] = Kss[(size_t)g * KDIM + t];
    __syncthreads();

    float a[4][4];
#pragma unroll
    for (int i = 0; i < 4; ++i)
#pragma unroll
        for (int j = 0; j < 4; ++j) a[i][j] = 0.f;
    for (int k = 0; k < 64; k += 4) {
        float qv[4][4], kv[4][4];
#pragma unroll
        for (int i = 0; i < 4; ++i) ld4(qv[i], &qs[ty * 4 + i][k]);
#pragma unroll
        for (int j = 0; j < 4; ++j) ld4(kv[j], &kT[swz(tx * 4 + j, k)]);
#pragma unroll
        for (int i = 0; i < 4; ++i)
#pragma unroll
            for (int j = 0; j < 4; ++j)
#pragma unroll
                for (int q = 0; q < 4; ++q)
                    a[i][j] = fmaf(qv[i][q], kv[j][q], a[i][j]);
    }
    float dpart[4];
#pragma unroll
    for (int i = 0; i < 4; ++i) {
        const int ri = ty * 4 + i;
        float s = 0.f;
#pragma unroll
        for (int j = 0; j < 4; ++j) {
            const int cj = tx * 4 + j;
            s += (cj <= ri) ? a[i][j] : 0.f;
        }
#pragma unroll
        for (int q = 0; q < 4; ++q)
            s += qs[ri][tx * 4 + q] * ksuml[tx * 4 + q];
        dpart[i] = s;
    }
#pragma unroll
    for (int m = 8; m >= 1; m >>= 1)
#pragma unroll
        for (int i = 0; i < 4; ++i)
            dpart[i] += __shfl_xor(dpart[i], m, 64);
    if (tx == 0) {
#pragma unroll
        for (int i = 0; i < 4; ++i) denl[ty * 4 + i] = dpart[i] + 1e-6f;
    }
#pragma unroll
    for (int i = 0; i < 4; ++i)
#pragma unroll
        for (int j = 0; j < 4; ++j)
            am[ty * 4 + i][tx * 4 + j] = ((tx * 4 + j) <= (ty * 4 + i)) ? a[i][j] : 0.f;
    __syncthreads();

    float acc[4][4];
#pragma unroll
    for (int i = 0; i < 4; ++i)
#pragma unroll
        for (int m = 0; m < 4; ++m) acc[i][m] = 0.f;
    for (int j = 0; j < 64; j += 4) {
        float av[4][4], vv[4][4];
#pragma unroll
        for (int i = 0; i < 4; ++i) ld4(av[i], &am[ty * 4 + i][j]);
#pragma unroll
        for (int jj = 0; jj < 4; ++jj) ld4(vv[jj], &vs[j + jj][tx * 4]);
#pragma unroll
        for (int jj = 0; jj < 4; ++jj)
#pragma unroll
            for (int i = 0; i < 4; ++i)
#pragma unroll
                for (int m = 0; m < 4; ++m)
                    acc[i][m] = fmaf(av[i][jj], vv[jj][m], acc[i][m]);
    }
    for (int k = 0; k < 64; k += 4) {
        float qv[4][4], sv[4][4];
#pragma unroll
        for (int i = 0; i < 4; ++i) ld4(qv[i], &qs[ty * 4 + i][k]);
#pragma unroll
        for (int kk = 0; kk < 4; ++kk) ld4(sv[kk], &ss[k + kk][tx * 4]);
#pragma unroll
        for (int kk = 0; kk < 4; ++kk)
#pragma unroll
            for (int i = 0; i < 4; ++i)
#pragma unroll
                for (int m = 0; m < 4; ++m)
                    acc[i][m] = fmaf(qv[i][kk], sv[kk][m], acc[i][m]);
    }
#pragma unroll
    for (int i = 0; i < 4; ++i) {
        const float dinv = 1.f / denl[ty * 4 + i];
#pragma unroll
        for (int m = 0; m < 4; ++m)
            Ob[((size_t)g * 64 + ty * 4 + i) * KDIM + tx * 4 + m] = f2bf(acc[i][m] * dinv);
    }
}

// ---------------- Kernel 5: output projection (bf16 MFMA, single-shot) ----------------
__global__ __launch_bounds__(256) void k_outproj(
    const ushort* __restrict__ Ob, const ushort* __restrict__ Woh,
    float* __restrict__ out)
{
    __shared__ ushort os[8 * 512];    // 8 KB
    __shared__ ushort wos[32 * 512];  // 32 KB
    const int t = threadIdx.x, w = t >> 6, l = t & 63;
    const int row0 = (blockIdx.x >> 2) * 64;
    const int c0 = (blockIdx.x & 3) * 256;

    {
        short8v otmp[2];
#pragma unroll
        for (int i = 0; i < 2; ++i) {
            const int s = t + i * 256;
            const int f = s >> 6;
            const int row = row0 + (f >> 1) * 16 + (s & 15);
            const int kk = (f & 1) * 32 + ((s >> 4) & 3) * 8;
            otmp[i] = *(const short8v*)&Ob[(size_t)row * KDIM + kk];
        }
        short8v wtmp[8];
#pragma unroll
        for (int i = 0; i < 8; ++i) {
            const int s = t + i * 256;
            const int f = s >> 6;
            const int n = c0 + (f >> 1) * 16 + (s & 15);
            const int kk = (f & 1) * 32 + ((s >> 4) & 3) * 8;
            wtmp[i] = *(const short8v*)&Woh[(size_t)n * KDIM + kk];
        }
#pragma unroll
        for (int i = 0; i < 2; ++i) *(short8v*)&os[(t + i * 256) * 8] = otmp[i];
#pragma unroll
        for (int i = 0; i < 8; ++i) *(short8v*)&wos[(t + i * 256) * 8] = wtmp[i];
    }
    __syncthreads();

    f32x4 acc[4][4];
#pragma unroll
    for (int r = 0; r < 4; ++r)
#pragma unroll
        for (int c = 0; c < 4; ++c) acc[r][c] = (f32x4){0.f, 0.f, 0.f, 0.f};
#pragma unroll
    for (int ks = 0; ks < 2; ++ks) {
        short8v a[4], b[4];
#pragma unroll
        for (int r = 0; r < 4; ++r)
            a[r] = *(const short8v*)&os[((r * 2 + ks) * 64 + l) * 8];
#pragma unroll
        for (int c = 0; c < 4; ++c) {
            const int cf = w * 4 + c;
            b[c] = *(const short8v*)&wos[((cf * 2 + ks) * 64 + l) * 8];
        }
#pragma unroll
        for (int c = 0; c < 4; ++c)
#pragma unroll
            for (int r = 0; r < 4; ++r)
                acc[r][c] = MFMA16(a[r], b[c], acc[r][c], 0, 0, 0);
    }
#pragma unroll
    for (int r = 0; r < 4; ++r) {
#pragma unroll
        for (int c = 0; c < 4; ++c) {
            const int col = c0 + (w * 4 + c) * 16 + (l & 15);
#pragma unroll
            for (int q = 0; q < 4; ++q) {
                const int row = row0 + r * 16 + ((l >> 4) << 2) + q;
                out[(size_t)row * DDIM + col] = acc[r][c][q];
            }
        }
    }
}

extern "C" void kernel_launch(void* const* d_in, const int* in_sizes, int n_in,
                              void* d_out, int out_size, void* d_ws, size_t ws_size,
                              hipStream_t stream)
{
    const float* x  = (const float*)d_in[0];
    const float* Wq = (const float*)d_in[1];
    const float* Wk = (const float*)d_in[2];
    const float* Wv = (const float*)d_in[3];
    const float* Wo = (const float*)d_in[4];
    float* out = (float*)d_out;

    float* ws  = (float*)d_ws;
    float* Q   = ws;                                   // 1M f32
    float* Kf  = Q   + (size_t)MROWS * KDIM;           // 1M
    float* V   = Kf  + (size_t)MROWS * KDIM;           // 1M
    float* KVc = V   + (size_t)MROWS * KDIM;           // 1M
    float* Sst = KVc + (size_t)TCHUNK * KDIM * KDIM;   // 1M
    float* Ksc = Sst + (size_t)TCHUNK * KDIM * KDIM;   // 16K
    float* Kss = Ksc + (size_t)TCHUNK * KDIM;          // 16K
    ushort* Obf = (ushort*)(Kss + (size_t)TCHUNK * KDIM);  // 1M bf16
    ushort* Wh  = Obf + (size_t)MROWS * KDIM;              // 192*1024 bf16
    ushort* Woh = Wh  + (size_t)192 * DDIM;                // 1024*64 bf16

    k_wconv<<<dim3(448), dim3(256), 0, stream>>>(Wq, Wk, Wv, Wo, Wh, Woh);
    k_proj<<<dim3(MROWS / 32), dim3(256), 0, stream>>>(x, Wh, Q, Kf, V);
    k_chunksum<<<dim3(TCHUNK), dim3(256), 0, stream>>>(Kf, V, KVc, Ksc);
    k_scan<<<dim3(BB * 65), dim3(64), 0, stream>>>(KVc, Ksc, Sst, Kss);
    k_intra<<<dim3(TCHUNK), dim3(256), 0, stream>>>(Q, Kf, V, Sst, Kss, Obf);
    k_outproj<<<dim3((MROWS / 64) * (DDIM / 256)), dim3(256), 0, stream>>>(Obf, Woh, out);
}

// Round 4
// 81.417 us; speedup vs baseline: 1.1078x; 1.1078x over previous
//
#include <hip/hip_runtime.h>

#define BB 4
#define SS 4096
#define DDIM 1024
#define KDIM 64
#define CHUNK 64
#define NCHUNK 64          // SS / CHUNK
#define TCHUNK 256         // BB * NCHUNK
#define MROWS 16384        // BB * SS

typedef short short8v __attribute__((ext_vector_type(8)));
typedef float f32x4 __attribute__((ext_vector_type(4)));
#define MFMA16 __builtin_amdgcn_mfma_f32_16x16x32_bf16

#define GLDS16(gp, lp) __builtin_amdgcn_global_load_lds( \
    (const __attribute__((address_space(1))) unsigned int*)(gp), \
    (__attribute__((address_space(3))) unsigned int*)(lp), 16, 0, 0)

__device__ __forceinline__ ushort f2bf(float f) {
    uint u = __float_as_uint(f);
    u += 0x7FFFu + ((u >> 16) & 1u);
    return (ushort)(u >> 16);
}

__device__ __forceinline__ void ld4(float* d, const float* p) {
    float4 v = *(const float4*)p;
    d[0] = v.x; d[1] = v.y; d[2] = v.z; d[3] = v.w;
}

// XOR swizzle used by k_intra's Kf tile
__device__ __forceinline__ int swz(int r, int c) {
    return r * 64 + ((((c >> 2) ^ ((r >> 2) & 7)) << 2) | (c & 3));
}

// ---------------- Kernel 0: weight conversion + fragment packing ----------------
// blocks 0..191: (s = b/12, cf = b%12) -> Whf fragment block, contiguous 1KB frags:
//   Whf[((s*12+cf)*2+ks)*512 + l*8 + e] = bf16( W[cf*16+(l&15)][s*64+ks*32+((l>>4)&3)*8+e] )
// blocks 192..447: Wo flat chunk -> Woh (row-major bf16, unchanged).
__global__ __launch_bounds__(256) void k_wconv(
    const float* __restrict__ Wq, const float* __restrict__ Wk,
    const float* __restrict__ Wv, const float* __restrict__ Wo,
    ushort* __restrict__ Whf, ushort* __restrict__ Woh)
{
    const int b = blockIdx.x, t = threadIdx.x;
    if (b < 192) {
        const int s = b / 12, cf = b % 12;
        const int ks = t >> 7;            // 0..1
        const int l = (t >> 1) & 63;      // lane
        const int half = t & 1;           // 4 floats each
        const int grow = cf * 16 + (l & 15);
        const int gcol = s * 64 + ks * 32 + ((l >> 4) & 3) * 8 + half * 4;
        const float* src = (grow < 64) ? (Wq + (size_t)grow * DDIM)
                         : (grow < 128) ? (Wk + (size_t)(grow - 64) * DDIM)
                                        : (Wv + (size_t)(grow - 128) * DDIM);
        float4 v = *(const float4*)&src[gcol];
        ushort h[4] = { f2bf(v.x), f2bf(v.y), f2bf(v.z), f2bf(v.w) };
        ushort* dst = &Whf[(size_t)(((s * 12 + cf) * 2 + ks) * 64 + l) * 8 + half * 4];
        *(ushort*)(dst + 0) = h[0]; *(ushort*)(dst + 1) = h[1];
        *(ushort*)(dst + 2) = h[2]; *(ushort*)(dst + 3) = h[3];
    } else {
        const int off = (b - 192) * 256 + t;
        Woh[off] = f2bf(Wo[off]);
    }
}

// ---------------- Kernel 1: fused QKV projection ----------------
// C[16384,192] = x @ [Wq;Wk;Wv]^T ; cols 0..127 get elu()+1.
// BM=32, BN=192, BK=64; grid=512 (2 blocks/CU), 4 waves, wave tile 32x48.
// Double-buffered LDS (2 x 28KB). W staged async via global_load_lds (frag-packed
// global source = coalesced 1KB per instr). x reg-staged coalesced + 1 ds_write_b128.
__global__ __launch_bounds__(256) void k_proj(
    const float* __restrict__ x, const ushort* __restrict__ Whf,
    float* __restrict__ Q, float* __restrict__ Kf, float* __restrict__ V)
{
    // per buffer: 4 A-frags (rf,ks) + 24 B-frags (cf,ks), 512 ushorts each
    __shared__ ushort lds[2 * 28 * 512];   // 56 KB
    const int t = threadIdx.x;
    const int w = t >> 6, l = t & 63;
    const int row0 = blockIdx.x * 32;

    // x staging geometry: thread t -> row r=t>>3, col chunk c8=(t&7)*8
    const int xr = t >> 3;
    const int c8 = (t & 7) * 8;
    const int xrf = xr >> 4;                       // 0..1
    const int xks = c8 >> 5;                       // 0..1
    const int xlane = (xr & 15) | (((c8 >> 3) & 3) << 4);
    const float* xsrc = &x[(size_t)(row0 + xr) * DDIM + c8];
    ushort* xdst_base = &lds[(size_t)(xrf * 2 + xks) * 512 + xlane * 8];

    // W staging: wave w stages frags f = w*6 + i; global is frag-packed
    // global ushort offset for step s, frag f, lane l: (s*24 + f)*512 + l*8
    // LDS: buf*14336 + (4 + f)*512  (wave-uniform base; HW adds lane*16B)

    auto stage = [&](int s, int buf) {
        ushort* lbase = &lds[(size_t)buf * 14336];
        // W: async global->LDS, 6 frags per wave
#pragma unroll
        for (int i = 0; i < 6; ++i) {
            const int f = w * 6 + i;
            const ushort* gp = &Whf[(size_t)(s * 24 + f) * 512 + l * 8];
            GLDS16(gp, lbase + (size_t)(4 + f) * 512);
        }
        // x: coalesced f32 loads -> cvt -> one ds_write_b128
        const float* xp = xsrc + s * 64;
        float4 u0 = *(const float4*)xp;
        float4 u1 = *(const float4*)(xp + 4);
        short8v h;
        h[0] = (short)f2bf(u0.x); h[1] = (short)f2bf(u0.y);
        h[2] = (short)f2bf(u0.z); h[3] = (short)f2bf(u0.w);
        h[4] = (short)f2bf(u1.x); h[5] = (short)f2bf(u1.y);
        h[6] = (short)f2bf(u1.z); h[7] = (short)f2bf(u1.w);
        *(short8v*)(lbase + (xdst_base - lds)) = h;
    };

    f32x4 acc[2][3];
#pragma unroll
    for (int r = 0; r < 2; ++r)
#pragma unroll
        for (int c = 0; c < 3; ++c) acc[r][c] = (f32x4){0.f, 0.f, 0.f, 0.f};

    stage(0, 0);
    __syncthreads();

    for (int step = 0; step < 16; ++step) {
        const int cur = step & 1, nxt = cur ^ 1;
        if (step < 15) stage(step + 1, nxt);   // async staging overlaps compute
        const ushort* cb = &lds[(size_t)cur * 14336];
#pragma unroll
        for (int ks = 0; ks < 2; ++ks) {
            short8v a0 = *(const short8v*)(cb + (size_t)(0 * 2 + ks) * 512 + l * 8);
            short8v a1 = *(const short8v*)(cb + (size_t)(1 * 2 + ks) * 512 + l * 8);
            short8v b0 = *(const short8v*)(cb + (size_t)(4 + (w * 3 + 0) * 2 + ks) * 512 + l * 8);
            short8v b1 = *(const short8v*)(cb + (size_t)(4 + (w * 3 + 1) * 2 + ks) * 512 + l * 8);
            short8v b2 = *(const short8v*)(cb + (size_t)(4 + (w * 3 + 2) * 2 + ks) * 512 + l * 8);
            acc[0][0] = MFMA16(a0, b0, acc[0][0], 0, 0, 0);
            acc[1][0] = MFMA16(a1, b0, acc[1][0], 0, 0, 0);
            acc[0][1] = MFMA16(a0, b1, acc[0][1], 0, 0, 0);
            acc[1][1] = MFMA16(a1, b1, acc[1][1], 0, 0, 0);
            acc[0][2] = MFMA16(a0, b2, acc[0][2], 0, 0, 0);
            acc[1][2] = MFMA16(a1, b2, acc[1][2], 0, 0, 0);
        }
        __syncthreads();   // drains vmcnt; next buffer staged & visible
    }

    // epilogue: C/D layout col=l&15, row=(l>>4)*4+q
#pragma unroll
    for (int rf = 0; rf < 2; ++rf) {
#pragma unroll
        for (int c = 0; c < 3; ++c) {
            const int col = w * 48 + c * 16 + (l & 15);
#pragma unroll
            for (int q = 0; q < 4; ++q) {
                const int row = row0 + rf * 16 + ((l >> 4) << 2) + q;
                float v = acc[rf][c][q];
                if (col < 128) v = (v > 0.f) ? v + 1.f : __expf(v);  // elu+1
                if (col < 64)       Q[(size_t)row * KDIM + col] = v;
                else if (col < 128) Kf[(size_t)row * KDIM + (col - 64)] = v;
                else                V[(size_t)row * KDIM + (col - 128)] = v;
            }
        }
    }
}

// ---------------- Kernel 2: per-chunk KV summary ----------------
__global__ __launch_bounds__(256) void k_chunksum(
    const float* __restrict__ Kf, const float* __restrict__ V,
    float* __restrict__ KVc, float* __restrict__ Ksc)
{
    __shared__ float ks[64][68];
    __shared__ float vs[64][68];
    const int g = blockIdx.x;
    const int t = threadIdx.x;
#pragma unroll
    for (int i = 0; i < 4; ++i) {
        const int f4 = i * 256 + t;
        const int r = f4 >> 4;
        const int kq = (f4 & 15) << 2;
        const size_t gi = ((size_t)g * 64 + r) * KDIM + kq;
        *(float4*)&ks[r][kq] = *(const float4*)&Kf[gi];
        *(float4*)&vs[r][kq] = *(const float4*)&V[gi];
    }
    __syncthreads();
    const int tx = t & 15, ty = t >> 4;
    float acc[4][4];
#pragma unroll
    for (int i = 0; i < 4; ++i)
#pragma unroll
        for (int m = 0; m < 4; ++m) acc[i][m] = 0.f;
    for (int j = 0; j < 64; ++j) {
        float ka[4], va[4];
        ld4(ka, &ks[j][ty * 4]);
        ld4(va, &vs[j][tx * 4]);
#pragma unroll
        for (int i = 0; i < 4; ++i)
#pragma unroll
            for (int m = 0; m < 4; ++m)
                acc[i][m] = fmaf(ka[i], va[m], acc[i][m]);
    }
#pragma unroll
    for (int i = 0; i < 4; ++i)
#pragma unroll
        for (int m = 0; m < 4; ++m)
            KVc[(size_t)g * 4096 + (size_t)(ty * 4 + i) * 64 + tx * 4 + m] = acc[i][m];
    if (t < 64) {
        float s = 0.f;
        for (int j = 0; j < 64; ++j) s += ks[j][t];
        Ksc[(size_t)g * KDIM + t] = s;
    }
}

// ---------------- Kernel 3: exclusive prefix over chunks (batched loads) ----------------
__global__ void k_scan(const float* __restrict__ KVc, const float* __restrict__ Ksc,
                       float* __restrict__ Sst, float* __restrict__ Kss)
{
    const int b = blockIdx.x / 65;
    const int r = blockIdx.x % 65;
    const int t = threadIdx.x;
    float acc = 0.f;
    if (r < 64) {
        const int e = r * 64 + t;
        for (int c0 = 0; c0 < NCHUNK; c0 += 8) {
            float v[8];
#pragma unroll
            for (int i = 0; i < 8; ++i)
                v[i] = KVc[((size_t)(b * NCHUNK + c0 + i)) * 4096 + e];
#pragma unroll
            for (int i = 0; i < 8; ++i) {
                Sst[((size_t)(b * NCHUNK + c0 + i)) * 4096 + e] = acc;
                acc += v[i];
            }
        }
    } else {
        for (int c0 = 0; c0 < NCHUNK; c0 += 8) {
            float v[8];
#pragma unroll
            for (int i = 0; i < 8; ++i)
                v[i] = Ksc[((size_t)(b * NCHUNK + c0 + i)) * KDIM + t];
#pragma unroll
            for (int i = 0; i < 8; ++i) {
                Kss[((size_t)(b * NCHUNK + c0 + i)) * KDIM + t] = acc;
                acc += v[i];
            }
        }
    }
}

// ---------------- Kernel 4: intra-chunk attention + state apply ----------------
__global__ __launch_bounds__(256) void k_intra(
    const float* __restrict__ Q, const float* __restrict__ Kf,
    const float* __restrict__ V, const float* __restrict__ Sst,
    const float* __restrict__ Kss, ushort* __restrict__ Ob)
{
    __shared__ float qs[64][68];
    __shared__ float kT[64 * 64];
    __shared__ float vs[64][68];
    __shared__ float ss[64][68];
    __shared__ float am[64][68];
    __shared__ float denl[64];
    __shared__ float ksuml[64];
    const int g = blockIdx.x;
    const int t = threadIdx.x;
    const int tx = t & 15, ty = t >> 4;
#pragma unroll
    for (int i = 0; i < 4; ++i) {
        const int f4 = i * 256 + t;
        const int r = f4 >> 4;
        const int kq = (f4 & 15) << 2;
        const size_t gi = ((size_t)g * 64 + r) * KDIM + kq;
        *(float4*)&qs[r][kq] = *(const float4*)&Q[gi];
        *(float4*)&kT[swz(r, kq)] = *(const float4*)&Kf[gi];
        *(float4*)&vs[r][kq] = *(const float4*)&V[gi];
        *(float4*)&ss[r][kq] = *(const float4*)&Sst[(size_t)g * 4096 + (size_t)f4 * 4];
    }
    if (t < 64) ksuml[t] = Kss[(size_t)g * KDIM + t];
    __syncthreads();

    float a[4][4];
#pragma unroll
    for (int i = 0; i < 4; ++i)
#pragma unroll
        for (int j = 0; j < 4; ++j) a[i][j] = 0.f;
    for (int k = 0; k < 64; k += 4) {
        float qv[4][4], kv[4][4];
#pragma unroll
        for (int i = 0; i < 4; ++i) ld4(qv[i], &qs[ty * 4 + i][k]);
#pragma unroll
        for (int j = 0; j < 4; ++j) ld4(kv[j], &kT[swz(tx * 4 + j, k)]);
#pragma unroll
        for (int i = 0; i < 4; ++i)
#pragma unroll
            for (int j = 0; j < 4; ++j)
#pragma unroll
                for (int q = 0; q < 4; ++q)
                    a[i][j] = fmaf(qv[i][q], kv[j][q], a[i][j]);
    }
    float dpart[4];
#pragma unroll
    for (int i = 0; i < 4; ++i) {
        const int ri = ty * 4 + i;
        float s = 0.f;
#pragma unroll
        for (int j = 0; j < 4; ++j) {
            const int cj = tx * 4 + j;
            s += (cj <= ri) ? a[i][j] : 0.f;
        }
#pragma unroll
        for (int q = 0; q < 4; ++q)
            s += qs[ri][tx * 4 + q] * ksuml[tx * 4 + q];
        dpart[i] = s;
    }
#pragma unroll
    for (int m = 8; m >= 1; m >>= 1)
#pragma unroll
        for (int i = 0; i < 4; ++i)
            dpart[i] += __shfl_xor(dpart[i], m, 64);
    if (tx == 0) {
#pragma unroll
        for (int i = 0; i < 4; ++i) denl[ty * 4 + i] = dpart[i] + 1e-6f;
    }
#pragma unroll
    for (int i = 0; i < 4; ++i)
#pragma unroll
        for (int j = 0; j < 4; ++j)
            am[ty * 4 + i][tx * 4 + j] = ((tx * 4 + j) <= (ty * 4 + i)) ? a[i][j] : 0.f;
    __syncthreads();

    float acc[4][4];
#pragma unroll
    for (int i = 0; i < 4; ++i)
#pragma unroll
        for (int m = 0; m < 4; ++m) acc[i][m] = 0.f;
    for (int j = 0; j < 64; j += 4) {
        float av[4][4], vv[4][4];
#pragma unroll
        for (int i = 0; i < 4; ++i) ld4(av[i], &am[ty * 4 + i][j]);
#pragma unroll
        for (int jj = 0; jj < 4; ++jj) ld4(vv[jj], &vs[j + jj][tx * 4]);
#pragma unroll
        for (int jj = 0; jj < 4; ++jj)
#pragma unroll
            for (int i = 0; i < 4; ++i)
#pragma unroll
                for (int m = 0; m < 4; ++m)
                    acc[i][m] = fmaf(av[i][jj], vv[jj][m], acc[i][m]);
    }
    for (int k = 0; k < 64; k += 4) {
        float qv[4][4], sv[4][4];
#pragma unroll
        for (int i = 0; i < 4; ++i) ld4(qv[i], &qs[ty * 4 + i][k]);
#pragma unroll
        for (int kk = 0; kk < 4; ++kk) ld4(sv[kk], &ss[k + kk][tx * 4]);
#pragma unroll
        for (int kk = 0; kk < 4; ++kk)
#pragma unroll
            for (int i = 0; i < 4; ++i)
#pragma unroll
                for (int m = 0; m < 4; ++m)
                    acc[i][m] = fmaf(qv[i][kk], sv[kk][m], acc[i][m]);
    }
#pragma unroll
    for (int i = 0; i < 4; ++i) {
        const float dinv = 1.f / denl[ty * 4 + i];
#pragma unroll
        for (int m = 0; m < 4; ++m)
            Ob[((size_t)g * 64 + ty * 4 + i) * KDIM + tx * 4 + m] = f2bf(acc[i][m] * dinv);
    }
}

// ---------------- Kernel 5: output projection (bf16 MFMA, single-shot) ----------------
__global__ __launch_bounds__(256) void k_outproj(
    const ushort* __restrict__ Ob, const ushort* __restrict__ Woh,
    float* __restrict__ out)
{
    __shared__ ushort os[8 * 512];    // 8 KB
    __shared__ ushort wos[32 * 512];  // 32 KB
    const int t = threadIdx.x, w = t >> 6, l = t & 63;
    const int row0 = (blockIdx.x >> 2) * 64;
    const int c0 = (blockIdx.x & 3) * 256;

    {
        short8v otmp[2];
#pragma unroll
        for (int i = 0; i < 2; ++i) {
            const int s = t + i * 256;
            const int f = s >> 6;
            const int row = row0 + (f >> 1) * 16 + (s & 15);
            const int kk = (f & 1) * 32 + ((s >> 4) & 3) * 8;
            otmp[i] = *(const short8v*)&Ob[(size_t)row * KDIM + kk];
        }
        short8v wtmp[8];
#pragma unroll
        for (int i = 0; i < 8; ++i) {
            const int s = t + i * 256;
            const int f = s >> 6;
            const int n = c0 + (f >> 1) * 16 + (s & 15);
            const int kk = (f & 1) * 32 + ((s >> 4) & 3) * 8;
            wtmp[i] = *(const short8v*)&Woh[(size_t)n * KDIM + kk];
        }
#pragma unroll
        for (int i = 0; i < 2; ++i) *(short8v*)&os[(t + i * 256) * 8] = otmp[i];
#pragma unroll
        for (int i = 0; i < 8; ++i) *(short8v*)&wos[(t + i * 256) * 8] = wtmp[i];
    }
    __syncthreads();

    f32x4 acc[4][4];
#pragma unroll
    for (int r = 0; r < 4; ++r)
#pragma unroll
        for (int c = 0; c < 4; ++c) acc[r][c] = (f32x4){0.f, 0.f, 0.f, 0.f};
#pragma unroll
    for (int ks = 0; ks < 2; ++ks) {
        short8v a[4], b[4];
#pragma unroll
        for (int r = 0; r < 4; ++r)
            a[r] = *(const short8v*)&os[((r * 2 + ks) * 64 + l) * 8];
#pragma unroll
        for (int c = 0; c < 4; ++c) {
            const int cf = w * 4 + c;
            b[c] = *(const short8v*)&wos[((cf * 2 + ks) * 64 + l) * 8];
        }
#pragma unroll
        for (int c = 0; c < 4; ++c)
#pragma unroll
            for (int r = 0; r < 4; ++r)
                acc[r][c] = MFMA16(a[r], b[c], acc[r][c], 0, 0, 0);
    }
#pragma unroll
    for (int r = 0; r < 4; ++r) {
#pragma unroll
        for (int c = 0; c < 4; ++c) {
            const int col = c0 + (w * 4 + c) * 16 + (l & 15);
#pragma unroll
            for (int q = 0; q < 4; ++q) {
                const int row = row0 + r * 16 + ((l >> 4) << 2) + q;
                out[(size_t)row * DDIM + col] = acc[r][c][q];
            }
        }
    }
}

extern "C" void kernel_launch(void* const* d_in, const int* in_sizes, int n_in,
                              void* d_out, int out_size, void* d_ws, size_t ws_size,
                              hipStream_t stream)
{
    const float* x  = (const float*)d_in[0];
    const float* Wq = (const float*)d_in[1];
    const float* Wk = (const float*)d_in[2];
    const float* Wv = (const float*)d_in[3];
    const float* Wo = (const float*)d_in[4];
    float* out = (float*)d_out;

    float* ws  = (float*)d_ws;
    float* Q   = ws;                                   // 1M f32
    float* Kf  = Q   + (size_t)MROWS * KDIM;           // 1M
    float* V   = Kf  + (size_t)MROWS * KDIM;           // 1M
    float* KVc = V   + (size_t)MROWS * KDIM;           // 1M
    float* Sst = KVc + (size_t)TCHUNK * KDIM * KDIM;   // 1M
    float* Ksc = Sst + (size_t)TCHUNK * KDIM * KDIM;   // 16K
    float* Kss = Ksc + (size_t)TCHUNK * KDIM;          // 16K
    ushort* Obf = (ushort*)(Kss + (size_t)TCHUNK * KDIM);  // 1M bf16
    ushort* Whf = Obf + (size_t)MROWS * KDIM;              // 192*1024 bf16 (frag-packed)
    ushort* Woh = Whf + (size_t)192 * DDIM;                // 1024*64 bf16

    k_wconv<<<dim3(448), dim3(256), 0, stream>>>(Wq, Wk, Wv, Wo, Whf, Woh);
    k_proj<<<dim3(MROWS / 32), dim3(256), 0, stream>>>(x, Whf, Q, Kf, V);
    k_chunksum<<<dim3(TCHUNK), dim3(256), 0, stream>>>(Kf, V, KVc, Ksc);
    k_scan<<<dim3(BB * 65), dim3(64), 0, stream>>>(KVc, Ksc, Sst, Kss);
    k_intra<<<dim3(TCHUNK), dim3(256), 0, stream>>>(Q, Kf, V, Sst, Kss, Obf);
    k_outproj<<<dim3((MROWS / 64) * (DDIM / 256)), dim3(256), 0, stream>>>(Obf, Woh, out);
}

// Round 5
// 79.874 us; speedup vs baseline: 1.1292x; 1.0193x over previous
//
#include <hip/hip_runtime.h>

#define BB 4
#define SS 4096
#define DDIM 1024
#define KDIM 64
#define CHUNK 64
#define NCHUNK 64          // SS / CHUNK
#define TCHUNK 256         // BB * NCHUNK
#define MROWS 16384        // BB * SS

typedef short short8v __attribute__((ext_vector_type(8)));
typedef float f32x4 __attribute__((ext_vector_type(4)));
#define MFMA16 __builtin_amdgcn_mfma_f32_16x16x32_bf16

__device__ __forceinline__ ushort f2bf(float f) {
    uint u = __float_as_uint(f);
    u += 0x7FFFu + ((u >> 16) & 1u);
    return (ushort)(u >> 16);
}

__device__ __forceinline__ void ld4(float* d, const float* p) {
    float4 v = *(const float4*)p;
    d[0] = v.x; d[1] = v.y; d[2] = v.z; d[3] = v.w;
}

// XOR swizzle for [64][64] f32 LDS tiles read with row-stride-4 lane patterns.
__device__ __forceinline__ int swz(int r, int c) {
    return r * 64 + ((((c >> 2) ^ ((r >> 2) & 7)) << 2) | (c & 3));
}

// ---------------- Kernel 0: weight conversion + fragment packing ----------------
// blocks 0..191: (s = b/12, cf = b%12) -> Whf fragment block, contiguous 1KB frags:
//   Whf[(s*24 + cf*2 + ks)*512 + l*8 + e] = bf16( W[cf*16+(l&15)][s*64+ks*32+((l>>4)&3)*8+e] )
// blocks 192..447: Wo flat chunk -> Woh (row-major bf16).
__global__ __launch_bounds__(256) void k_wconv(
    const float* __restrict__ Wq, const float* __restrict__ Wk,
    const float* __restrict__ Wv, const float* __restrict__ Wo,
    ushort* __restrict__ Whf, ushort* __restrict__ Woh)
{
    const int b = blockIdx.x, t = threadIdx.x;
    if (b < 192) {
        const int s = b / 12, cf = b % 12;
        const int ks = t >> 7;            // 0..1
        const int l = (t >> 1) & 63;      // lane
        const int half = t & 1;           // 4 floats each
        const int grow = cf * 16 + (l & 15);
        const int gcol = s * 64 + ks * 32 + ((l >> 4) & 3) * 8 + half * 4;
        const float* src = (grow < 64) ? (Wq + (size_t)grow * DDIM)
                         : (grow < 128) ? (Wk + (size_t)(grow - 64) * DDIM)
                                        : (Wv + (size_t)(grow - 128) * DDIM);
        float4 v = *(const float4*)&src[gcol];
        ushort h[4] = { f2bf(v.x), f2bf(v.y), f2bf(v.z), f2bf(v.w) };
        ushort* dst = &Whf[(size_t)(((s * 12 + cf) * 2 + ks) * 64 + l) * 8 + half * 4];
        dst[0] = h[0]; dst[1] = h[1]; dst[2] = h[2]; dst[3] = h[3];
    } else {
        const int off = (b - 192) * 256 + t;
        Woh[off] = f2bf(Wo[off]);
    }
}

// ---------------- Kernel 1: fused QKV projection ----------------
// C[16384,192] = x @ [Wq;Wk;Wv]^T ; cols 0..127 get elu()+1.
// BM=32, BN=192; grid=512 (2 blocks/CU), 4 waves, wave tile 32x48.
// x staged ONCE (64KB LDS, one barrier). W streamed global->reg from the
// frag-packed layout (each load = 64 lanes x 16B contiguous = coalesced),
// named double-buffer, NO barriers in the K-loop.
__global__ __launch_bounds__(256) void k_proj(
    const float* __restrict__ x, const ushort* __restrict__ Whf,
    float* __restrict__ Q, float* __restrict__ Kf, float* __restrict__ V)
{
    // frag (rf*32+kk), kk=0..31: lane l holds x[row0+rf*16+(l&15)][kk*32+((l>>4)&3)*8+0..7]
    __shared__ ushort xs[64 * 512];   // 64 KB
    const int t = threadIdx.x;
    const int w = t >> 6, l = t & 63;
    const int row0 = blockIdx.x * 32;

    // ---- stage x: thread t -> row t&31, k-range (t>>5)*128..+127 ----
    {
        const int r = t & 31;
        const int kb = (t >> 5) * 128;
        const int rf = r >> 4, rl = r & 15;
        const float* xrow = &x[(size_t)(row0 + r) * DDIM + kb];
#pragma unroll
        for (int kc = 0; kc < 128; kc += 8) {
            float4 u0 = *(const float4*)(xrow + kc);
            float4 u1 = *(const float4*)(xrow + kc + 4);
            short8v h;
            h[0] = (short)f2bf(u0.x); h[1] = (short)f2bf(u0.y);
            h[2] = (short)f2bf(u0.z); h[3] = (short)f2bf(u0.w);
            h[4] = (short)f2bf(u1.x); h[5] = (short)f2bf(u1.y);
            h[6] = (short)f2bf(u1.z); h[7] = (short)f2bf(u1.w);
            const int k = kb + kc;
            const int frag = rf * 32 + (k >> 5);
            const int lane = rl | (((k >> 3) & 3) << 4);
            *(short8v*)&xs[(size_t)(frag * 64 + lane) * 8] = h;
        }
    }
    __syncthreads();

    f32x4 acc[2][3];
#pragma unroll
    for (int r = 0; r < 2; ++r)
#pragma unroll
        for (int c = 0; c < 3; ++c) acc[r][c] = (f32x4){0.f, 0.f, 0.f, 0.f};

    // W frag load: step s, j = c*2+ks
    auto loadW = [&](int s, short8v (&bw)[6]) {
#pragma unroll
        for (int j = 0; j < 6; ++j) {
            const int cf = w * 3 + (j >> 1);
            const int f = cf * 2 + (j & 1);
            bw[j] = *(const short8v*)&Whf[((size_t)(s * 24 + f)) * 512 + l * 8];
        }
    };
    auto computeStep = [&](int s, short8v (&bw)[6]) {
#pragma unroll
        for (int ks = 0; ks < 2; ++ks) {
            const int kk = s * 2 + ks;
            short8v a0 = *(const short8v*)&xs[(size_t)((kk) * 64 + l) * 8];
            short8v a1 = *(const short8v*)&xs[(size_t)((32 + kk) * 64 + l) * 8];
#pragma unroll
            for (int c = 0; c < 3; ++c) {
                acc[0][c] = MFMA16(a0, bw[c * 2 + ks], acc[0][c], 0, 0, 0);
                acc[1][c] = MFMA16(a1, bw[c * 2 + ks], acc[1][c], 0, 0, 0);
            }
        }
    };

    short8v bwA[6], bwB[6];
    loadW(0, bwA);
    for (int s = 0; s < 16; s += 2) {
        loadW(s + 1, bwB);
        computeStep(s, bwA);
        if (s + 2 < 16) loadW(s + 2, bwA);
        computeStep(s + 1, bwB);
    }

    // epilogue: C/D layout col=l&15, row=(l>>4)*4+q
#pragma unroll
    for (int rf = 0; rf < 2; ++rf) {
#pragma unroll
        for (int c = 0; c < 3; ++c) {
            const int col = w * 48 + c * 16 + (l & 15);
#pragma unroll
            for (int q = 0; q < 4; ++q) {
                const int row = row0 + rf * 16 + ((l >> 4) << 2) + q;
                float v = acc[rf][c][q];
                if (col < 128) v = (v > 0.f) ? v + 1.f : __expf(v);  // elu+1
                if (col < 64)       Q[(size_t)row * KDIM + col] = v;
                else if (col < 128) Kf[(size_t)row * KDIM + (col - 64)] = v;
                else                V[(size_t)row * KDIM + (col - 128)] = v;
            }
        }
    }
}

// ---------------- Kernel 2: per-chunk KV summary ----------------
__global__ __launch_bounds__(256) void k_chunksum(
    const float* __restrict__ Kf, const float* __restrict__ V,
    float* __restrict__ KVc, float* __restrict__ Ksc)
{
    __shared__ float ks[64][68];
    __shared__ float vs[64][68];
    const int g = blockIdx.x;
    const int t = threadIdx.x;
#pragma unroll
    for (int i = 0; i < 4; ++i) {
        const int f4 = i * 256 + t;
        const int r = f4 >> 4;
        const int kq = (f4 & 15) << 2;
        const size_t gi = ((size_t)g * 64 + r) * KDIM + kq;
        *(float4*)&ks[r][kq] = *(const float4*)&Kf[gi];
        *(float4*)&vs[r][kq] = *(const float4*)&V[gi];
    }
    __syncthreads();
    const int tx = t & 15, ty = t >> 4;
    float acc[4][4];
#pragma unroll
    for (int i = 0; i < 4; ++i)
#pragma unroll
        for (int m = 0; m < 4; ++m) acc[i][m] = 0.f;
    for (int j = 0; j < 64; ++j) {
        float ka[4], va[4];
        ld4(ka, &ks[j][ty * 4]);
        ld4(va, &vs[j][tx * 4]);
#pragma unroll
        for (int i = 0; i < 4; ++i)
#pragma unroll
            for (int m = 0; m < 4; ++m)
                acc[i][m] = fmaf(ka[i], va[m], acc[i][m]);
    }
#pragma unroll
    for (int i = 0; i < 4; ++i)
#pragma unroll
        for (int m = 0; m < 4; ++m)
            KVc[(size_t)g * 4096 + (size_t)(ty * 4 + i) * 64 + tx * 4 + m] = acc[i][m];
    if (t < 64) {
        float s = 0.f;
        for (int j = 0; j < 64; ++j) s += ks[j][t];
        Ksc[(size_t)g * KDIM + t] = s;
    }
}

// ---------------- Kernel 3: exclusive prefix over chunks (batched loads) ----------------
__global__ void k_scan(const float* __restrict__ KVc, const float* __restrict__ Ksc,
                       float* __restrict__ Sst, float* __restrict__ Kss)
{
    const int b = blockIdx.x / 65;
    const int r = blockIdx.x % 65;
    const int t = threadIdx.x;
    float acc = 0.f;
    if (r < 64) {
        const int e = r * 64 + t;
        for (int c0 = 0; c0 < NCHUNK; c0 += 8) {
            float v[8];
#pragma unroll
            for (int i = 0; i < 8; ++i)
                v[i] = KVc[((size_t)(b * NCHUNK + c0 + i)) * 4096 + e];
#pragma unroll
            for (int i = 0; i < 8; ++i) {
                Sst[((size_t)(b * NCHUNK + c0 + i)) * 4096 + e] = acc;
                acc += v[i];
            }
        }
    } else {
        for (int c0 = 0; c0 < NCHUNK; c0 += 8) {
            float v[8];
#pragma unroll
            for (int i = 0; i < 8; ++i)
                v[i] = Ksc[((size_t)(b * NCHUNK + c0 + i)) * KDIM + t];
#pragma unroll
            for (int i = 0; i < 8; ++i) {
                Kss[((size_t)(b * NCHUNK + c0 + i)) * KDIM + t] = acc;
                acc += v[i];
            }
        }
    }
}

// ---------------- Kernel 4: intra-chunk attention + state apply ----------------
// LDS 69KB (was 87KB): masked-A tile reuses kT's space (swizzled) -> 2 blocks/CU.
__global__ __launch_bounds__(256) void k_intra(
    const float* __restrict__ Q, const float* __restrict__ Kf,
    const float* __restrict__ V, const float* __restrict__ Sst,
    const float* __restrict__ Kss, ushort* __restrict__ Ob)
{
    __shared__ float qs[64][68];
    __shared__ float kT[64 * 64];   // phase 1: swizzled Kf ; phase 2: swizzled masked A
    __shared__ float vs[64][68];
    __shared__ float ss[64][68];
    __shared__ float denl[64];
    __shared__ float ksuml[64];
    const int g = blockIdx.x;
    const int t = threadIdx.x;
    const int tx = t & 15, ty = t >> 4;
#pragma unroll
    for (int i = 0; i < 4; ++i) {
        const int f4 = i * 256 + t;
        const int r = f4 >> 4;
        const int kq = (f4 & 15) << 2;
        const size_t gi = ((size_t)g * 64 + r) * KDIM + kq;
        *(float4*)&qs[r][kq] = *(const float4*)&Q[gi];
        *(float4*)&kT[swz(r, kq)] = *(const float4*)&Kf[gi];
        *(float4*)&vs[r][kq] = *(const float4*)&V[gi];
        *(float4*)&ss[r][kq] = *(const float4*)&Sst[(size_t)g * 4096 + (size_t)f4 * 4];
    }
    if (t < 64) ksuml[t] = Kss[(size_t)g * KDIM + t];
    __syncthreads();

    float a[4][4];
#pragma unroll
    for (int i = 0; i < 4; ++i)
#pragma unroll
        for (int j = 0; j < 4; ++j) a[i][j] = 0.f;
    for (int k = 0; k < 64; k += 4) {
        float qv[4][4], kv[4][4];
#pragma unroll
        for (int i = 0; i < 4; ++i) ld4(qv[i], &qs[ty * 4 + i][k]);
#pragma unroll
        for (int j = 0; j < 4; ++j) ld4(kv[j], &kT[swz(tx * 4 + j, k)]);
#pragma unroll
        for (int i = 0; i < 4; ++i)
#pragma unroll
            for (int j = 0; j < 4; ++j)
#pragma unroll
                for (int q = 0; q < 4; ++q)
                    a[i][j] = fmaf(qv[i][q], kv[j][q], a[i][j]);
    }
    __syncthreads();   // all kT (Kf) reads done before A overwrites it

    float dpart[4];
#pragma unroll
    for (int i = 0; i < 4; ++i) {
        const int ri = ty * 4 + i;
        float s = 0.f;
#pragma unroll
        for (int j = 0; j < 4; ++j) {
            const int cj = tx * 4 + j;
            s += (cj <= ri) ? a[i][j] : 0.f;
        }
#pragma unroll
        for (int q = 0; q < 4; ++q)
            s += qs[ri][tx * 4 + q] * ksuml[tx * 4 + q];
        dpart[i] = s;
    }
#pragma unroll
    for (int m = 8; m >= 1; m >>= 1)
#pragma unroll
        for (int i = 0; i < 4; ++i)
            dpart[i] += __shfl_xor(dpart[i], m, 64);
    if (tx == 0) {
#pragma unroll
        for (int i = 0; i < 4; ++i) denl[ty * 4 + i] = dpart[i] + 1e-6f;
    }
    // store causal-masked A into kT's space (swizzled)
#pragma unroll
    for (int i = 0; i < 4; ++i)
#pragma unroll
        for (int j = 0; j < 4; ++j)
            kT[swz(ty * 4 + i, tx * 4 + j)] =
                ((tx * 4 + j) <= (ty * 4 + i)) ? a[i][j] : 0.f;
    __syncthreads();

    float acc[4][4];
#pragma unroll
    for (int i = 0; i < 4; ++i)
#pragma unroll
        for (int m = 0; m < 4; ++m) acc[i][m] = 0.f;
    for (int j = 0; j < 64; j += 4) {
        float av[4][4], vv[4][4];
#pragma unroll
        for (int i = 0; i < 4; ++i) ld4(av[i], &kT[swz(ty * 4 + i, j)]);
#pragma unroll
        for (int jj = 0; jj < 4; ++jj) ld4(vv[jj], &vs[j + jj][tx * 4]);
#pragma unroll
        for (int jj = 0; jj < 4; ++jj)
#pragma unroll
            for (int i = 0; i < 4; ++i)
#pragma unroll
                for (int m = 0; m < 4; ++m)
                    acc[i][m] = fmaf(av[i][jj], vv[jj][m], acc[i][m]);
    }
    for (int k = 0; k < 64; k += 4) {
        float qv[4][4], sv[4][4];
#pragma unroll
        for (int i = 0; i < 4; ++i) ld4(qv[i], &qs[ty * 4 + i][k]);
#pragma unroll
        for (int kk = 0; kk < 4; ++kk) ld4(sv[kk], &ss[k + kk][tx * 4]);
#pragma unroll
        for (int kk = 0; kk < 4; ++kk)
#pragma unroll
            for (int i = 0; i < 4; ++i)
#pragma unroll
                for (int m = 0; m < 4; ++m)
                    acc[i][m] = fmaf(qv[i][kk], sv[kk][m], acc[i][m]);
    }
#pragma unroll
    for (int i = 0; i < 4; ++i) {
        const float dinv = 1.f / denl[ty * 4 + i];
#pragma unroll
        for (int m = 0; m < 4; ++m)
            Ob[((size_t)g * 64 + ty * 4 + i) * KDIM + tx * 4 + m] = f2bf(acc[i][m] * dinv);
    }
}

// ---------------- Kernel 5: output projection (bf16 MFMA, single-shot) ----------------
__global__ __launch_bounds__(256) void k_outproj(
    const ushort* __restrict__ Ob, const ushort* __restrict__ Woh,
    float* __restrict__ out)
{
    __shared__ ushort os[8 * 512];    // 8 KB
    __shared__ ushort wos[32 * 512];  // 32 KB
    const int t = threadIdx.x, w = t >> 6, l = t & 63;
    const int row0 = (blockIdx.x >> 2) * 64;
    const int c0 = (blockIdx.x & 3) * 256;

    {
        short8v otmp[2];
#pragma unroll
        for (int i = 0; i < 2; ++i) {
            const int s = t + i * 256;
            const int f = s >> 6;
            const int row = row0 + (f >> 1) * 16 + (s & 15);
            const int kk = (f & 1) * 32 + ((s >> 4) & 3) * 8;
            otmp[i] = *(const short8v*)&Ob[(size_t)row * KDIM + kk];
        }
        short8v wtmp[8];
#pragma unroll
        for (int i = 0; i < 8; ++i) {
            const int s = t + i * 256;
            const int f = s >> 6;
            const int n = c0 + (f >> 1) * 16 + (s & 15);
            const int kk = (f & 1) * 32 + ((s >> 4) & 3) * 8;
            wtmp[i] = *(const short8v*)&Woh[(size_t)n * KDIM + kk];
        }
#pragma unroll
        for (int i = 0; i < 2; ++i) *(short8v*)&os[(t + i * 256) * 8] = otmp[i];
#pragma unroll
        for (int i = 0; i < 8; ++i) *(short8v*)&wos[(t + i * 256) * 8] = wtmp[i];
    }
    __syncthreads();

    f32x4 acc[4][4];
#pragma unroll
    for (int r = 0; r < 4; ++r)
#pragma unroll
        for (int c = 0; c < 4; ++c) acc[r][c] = (f32x4){0.f, 0.f, 0.f, 0.f};
#pragma unroll
    for (int ks = 0; ks < 2; ++ks) {
        short8v a[4], b[4];
#pragma unroll
        for (int r = 0; r < 4; ++r)
            a[r] = *(const short8v*)&os[((r * 2 + ks) * 64 + l) * 8];
#pragma unroll
        for (int c = 0; c < 4; ++c) {
            const int cf = w * 4 + c;
            b[c] = *(const short8v*)&wos[((cf * 2 + ks) * 64 + l) * 8];
        }
#pragma unroll
        for (int c = 0; c < 4; ++c)
#pragma unroll
            for (int r = 0; r < 4; ++r)
                acc[r][c] = MFMA16(a[r], b[c], acc[r][c], 0, 0, 0);
    }
#pragma unroll
    for (int r = 0; r < 4; ++r) {
#pragma unroll
        for (int c = 0; c < 4; ++c) {
            const int col = c0 + (w * 4 + c) * 16 + (l & 15);
#pragma unroll
            for (int q = 0; q < 4; ++q) {
                const int row = row0 + r * 16 + ((l >> 4) << 2) + q;
                out[(size_t)row * DDIM + col] = acc[r][c][q];
            }
        }
    }
}

extern "C" void kernel_launch(void* const* d_in, const int* in_sizes, int n_in,
                              void* d_out, int out_size, void* d_ws, size_t ws_size,
                              hipStream_t stream)
{
    const float* x  = (const float*)d_in[0];
    const float* Wq = (const float*)d_in[1];
    const float* Wk = (const float*)d_in[2];
    const float* Wv = (const float*)d_in[3];
    const float* Wo = (const float*)d_in[4];
    float* out = (float*)d_out;

    float* ws  = (float*)d_ws;
    float* Q   = ws;                                   // 1M f32
    float* Kf  = Q   + (size_t)MROWS * KDIM;           // 1M
    float* V   = Kf  + (size_t)MROWS * KDIM;           // 1M
    float* KVc = V   + (size_t)MROWS * KDIM;           // 1M
    float* Sst = KVc + (size_t)TCHUNK * KDIM * KDIM;   // 1M
    float* Ksc = Sst + (size_t)TCHUNK * KDIM * KDIM;   // 16K
    float* Kss = Ksc + (size_t)TCHUNK * KDIM;          // 16K
    ushort* Obf = (ushort*)(Kss + (size_t)TCHUNK * KDIM);  // 1M bf16
    ushort* Whf = Obf + (size_t)MROWS * KDIM;              // 192*1024 bf16 (frag-packed)
    ushort* Woh = Whf + (size_t)192 * DDIM;                // 1024*64 bf16

    k_wconv<<<dim3(448), dim3(256), 0, stream>>>(Wq, Wk, Wv, Wo, Whf, Woh);
    k_proj<<<dim3(MROWS / 32), dim3(256), 0, stream>>>(x, Whf, Q, Kf, V);
    k_chunksum<<<dim3(TCHUNK), dim3(256), 0, stream>>>(Kf, V, KVc, Ksc);
    k_scan<<<dim3(BB * 65), dim3(64), 0, stream>>>(KVc, Ksc, Sst, Kss);
    k_intra<<<dim3(TCHUNK), dim3(256), 0, stream>>>(Q, Kf, V, Sst, Kss, Obf);
    k_outproj<<<dim3((MROWS / 64) * (DDIM / 256)), dim3(256), 0, stream>>>(Obf, Woh, out);
}

// Round 6
// 64.065 us; speedup vs baseline: 1.4078x; 1.2468x over previous
//
#include <hip/hip_runtime.h>

#define BB 4
#define SS 4096
#define DDIM 1024
#define KDIM 64
#define NCHUNK 64          // SS / CHUNK
#define TCHUNK 256         // BB * NCHUNK
#define MROWS 16384        // BB * SS

typedef short short8v __attribute__((ext_vector_type(8)));
typedef float f32x4 __attribute__((ext_vector_type(4)));
#define MFMA16 __builtin_amdgcn_mfma_f32_16x16x32_bf16

__device__ __forceinline__ ushort f2bf(float f) {
    uint u = __float_as_uint(f);
    u += 0x7FFFu + ((u >> 16) & 1u);
    return (ushort)(u >> 16);
}

// ---------------- Kernel 0: weight conversion + fragment packing ----------------
// b<192: Whf frag-packed [s16][cf12][ks2] frags of 512 ushorts (as R5).
// b>=192: Wof frag-packed [cf64][ks2]: lane l holds Wo[cf*16+(l&15)][ks*32+((l>>4)&3)*8+e].
__global__ __launch_bounds__(256) void k_wconv(
    const float* __restrict__ Wq, const float* __restrict__ Wk,
    const float* __restrict__ Wv, const float* __restrict__ Wo,
    ushort* __restrict__ Whf, ushort* __restrict__ Wof)
{
    const int b = blockIdx.x, t = threadIdx.x;
    const int ks = t >> 7;            // 0..1
    const int l = (t >> 1) & 63;      // lane
    const int half = t & 1;           // low/high 4 elems
    if (b < 192) {
        const int s = b / 12, cf = b % 12;
        const int grow = cf * 16 + (l & 15);
        const int gcol = s * 64 + ks * 32 + ((l >> 4) & 3) * 8 + half * 4;
        const float* src = (grow < 64) ? (Wq + (size_t)grow * DDIM)
                         : (grow < 128) ? (Wk + (size_t)(grow - 64) * DDIM)
                                        : (Wv + (size_t)(grow - 128) * DDIM);
        float4 v = *(const float4*)&src[gcol];
        ushort* dst = &Whf[(size_t)(((s * 12 + cf) * 2 + ks) * 64 + l) * 8 + half * 4];
        dst[0] = f2bf(v.x); dst[1] = f2bf(v.y); dst[2] = f2bf(v.z); dst[3] = f2bf(v.w);
    } else {
        const int cf = b - 192;           // 0..63
        const int d = cf * 16 + (l & 15);
        const int kc = ks * 32 + ((l >> 4) & 3) * 8 + half * 4;
        float4 v = *(const float4*)&Wo[(size_t)d * KDIM + kc];
        ushort* dst = &Wof[(size_t)((cf * 2 + ks) * 64 + l) * 8 + half * 4];
        dst[0] = f2bf(v.x); dst[1] = f2bf(v.y); dst[2] = f2bf(v.z); dst[3] = f2bf(v.w);
    }
}

// ---------------- Kernel 1: fused QKV projection -> frag-packed bf16 ----------------
// BM=32, grid=512. Main loop = R5 (x staged once, W reg-streamed, barrier-free).
// Epilogue: transpose via LDS -> Qf/Kff row-frags + KfT/VT transposed frags.
#define EBP 216   // eb row pitch (ushorts): 432B = 16B-aligned rows, odd/32 bank spread
__global__ __launch_bounds__(256) void k_proj(
    const float* __restrict__ x, const ushort* __restrict__ Whf,
    ushort* __restrict__ Qf, ushort* __restrict__ Kff,
    ushort* __restrict__ KfT, ushort* __restrict__ VT)
{
    __shared__ ushort xs[64 * 512];   // 64 KB; reused as eb[32][EBP] in epilogue
    const int t = threadIdx.x;
    const int w = t >> 6, l = t & 63;
    const int mb = blockIdx.x;
    const int row0 = mb * 32;

    // ---- stage x: thread t -> row t&31, k-range (t>>5)*128..+127 ----
    {
        const int r = t & 31;
        const int kb = (t >> 5) * 128;
        const int rf = r >> 4, rl = r & 15;
        const float* xrow = &x[(size_t)(row0 + r) * DDIM + kb];
#pragma unroll
        for (int kc = 0; kc < 128; kc += 8) {
            float4 u0 = *(const float4*)(xrow + kc);
            float4 u1 = *(const float4*)(xrow + kc + 4);
            short8v h;
            h[0] = (short)f2bf(u0.x); h[1] = (short)f2bf(u0.y);
            h[2] = (short)f2bf(u0.z); h[3] = (short)f2bf(u0.w);
            h[4] = (short)f2bf(u1.x); h[5] = (short)f2bf(u1.y);
            h[6] = (short)f2bf(u1.z); h[7] = (short)f2bf(u1.w);
            const int k = kb + kc;
            const int frag = rf * 32 + (k >> 5);
            const int lane = rl | (((k >> 3) & 3) << 4);
            *(short8v*)&xs[(size_t)(frag * 64 + lane) * 8] = h;
        }
    }
    __syncthreads();

    f32x4 acc[2][3];
#pragma unroll
    for (int r = 0; r < 2; ++r)
#pragma unroll
        for (int c = 0; c < 3; ++c) acc[r][c] = (f32x4){0.f, 0.f, 0.f, 0.f};

    auto loadW = [&](int s, short8v (&bw)[6]) {
#pragma unroll
        for (int j = 0; j < 6; ++j) {
            const int cf = w * 3 + (j >> 1);
            const int f = cf * 2 + (j & 1);
            bw[j] = *(const short8v*)&Whf[((size_t)(s * 24 + f)) * 512 + l * 8];
        }
    };
    auto computeStep = [&](int s, short8v (&bw)[6]) {
#pragma unroll
        for (int ks = 0; ks < 2; ++ks) {
            const int kk = s * 2 + ks;
            short8v a0 = *(const short8v*)&xs[(size_t)((kk) * 64 + l) * 8];
            short8v a1 = *(const short8v*)&xs[(size_t)((32 + kk) * 64 + l) * 8];
#pragma unroll
            for (int c = 0; c < 3; ++c) {
                acc[0][c] = MFMA16(a0, bw[c * 2 + ks], acc[0][c], 0, 0, 0);
                acc[1][c] = MFMA16(a1, bw[c * 2 + ks], acc[1][c], 0, 0, 0);
            }
        }
    };

    short8v bwA[6], bwB[6];
    loadW(0, bwA);
    for (int s = 0; s < 16; s += 2) {
        loadW(s + 1, bwB);
        computeStep(s, bwA);
        if (s + 2 < 16) loadW(s + 2, bwA);
        computeStep(s + 1, bwB);
    }

    // ---- epilogue: C-layout -> eb[32][EBP] (elu+1 on cols<128) ----
    __syncthreads();                       // all waves done reading xs
    ushort* eb = xs;
#pragma unroll
    for (int rf = 0; rf < 2; ++rf)
#pragma unroll
        for (int c = 0; c < 3; ++c) {
            const int col = w * 48 + c * 16 + (l & 15);
#pragma unroll
            for (int q = 0; q < 4; ++q) {
                const int rl = rf * 16 + ((l >> 4) << 2) + q;
                float v = acc[rf][c][q];
                if (col < 128) v = (v > 0.f) ? v + 1.f : __expf(v);  // elu+1
                eb[rl * EBP + col] = f2bf(v);
            }
        }
    __syncthreads();

    // ---- row-frag stores: Qf/Kff [mb][rf2][ks2] ----
    {
        const int rf = t >> 7, ks = (t >> 6) & 1, lam = t & 63;
        const int r = rf * 16 + (lam & 15);
        const int c0 = ks * 32 + ((lam >> 4) & 3) * 8;
        short8v q8 = *(const short8v*)&eb[r * EBP + c0];
        short8v k8 = *(const short8v*)&eb[r * EBP + 64 + c0];
        const size_t fo = ((size_t)(mb * 4 + rf * 2 + ks)) * 512 + lam * 8;
        *(short8v*)&Qf[fo] = q8;
        *(short8v*)&Kff[fo] = k8;
    }
    // ---- T-frag stores: KfT/VT [g][f4][js2], g=mb>>1, js=mb&1 ----
    {
        const int f = t >> 6, lam = t & 63;
        const int kcol = 64 + f * 16 + (lam & 15);
        const int vcol = 128 + f * 16 + (lam & 15);
        const int jb = ((lam >> 4) & 3) * 8;
        short8v kT, vT;
#pragma unroll
        for (int e = 0; e < 8; ++e) {
            kT[e] = (short)eb[(jb + e) * EBP + kcol];
            vT[e] = (short)eb[(jb + e) * EBP + vcol];
        }
        const size_t fo = ((size_t)((mb >> 1) * 8 + f * 2 + (mb & 1))) * 512 + lam * 8;
        *(short8v*)&KfT[fo] = kT;
        *(short8v*)&VT[fo] = vT;
    }
}

// ---------------- Kernel 2: per-chunk KV summary (MFMA, 1 wave/block) ----------------
// KVc[k][m] = sum_j Kf[j][k]V[j][m] via mfma(KfT, VT); ones-col frag -> Ksc in col 64.
__global__ __launch_bounds__(64) void k_chunksum(
    const ushort* __restrict__ KfT, const ushort* __restrict__ VT,
    float* __restrict__ KVc, float* __restrict__ Ksc)
{
    const int g = blockIdx.x, l = threadIdx.x;
    short8v ka[4][2], vb[4][2];
#pragma unroll
    for (int f = 0; f < 4; ++f)
#pragma unroll
        for (int js = 0; js < 2; ++js) {
            const size_t fo = ((size_t)(g * 8 + f * 2 + js)) * 512 + l * 8;
            ka[f][js] = *(const short8v*)&KfT[fo];
            vb[f][js] = *(const short8v*)&VT[fo];
        }
    short8v onesf;
#pragma unroll
    for (int e = 0; e < 8; ++e) onesf[e] = ((l & 15) == 0) ? (short)0x3F80 : (short)0;

    f32x4 acc[4][5];
#pragma unroll
    for (int kf = 0; kf < 4; ++kf)
#pragma unroll
        for (int mf = 0; mf < 5; ++mf) acc[kf][mf] = (f32x4){0.f, 0.f, 0.f, 0.f};
#pragma unroll
    for (int js = 0; js < 2; ++js)
#pragma unroll
        for (int kf = 0; kf < 4; ++kf) {
#pragma unroll
            for (int mf = 0; mf < 4; ++mf)
                acc[kf][mf] = MFMA16(ka[kf][js], vb[mf][js], acc[kf][mf], 0, 0, 0);
            acc[kf][4] = MFMA16(ka[kf][js], onesf, acc[kf][4], 0, 0, 0);
        }
    const int lq = l >> 4;
#pragma unroll
    for (int kf = 0; kf < 4; ++kf) {
#pragma unroll
        for (int q = 0; q < 4; ++q) {
            const int k = kf * 16 + lq * 4 + q;
#pragma unroll
            for (int mf = 0; mf < 4; ++mf)
                KVc[(size_t)g * 4096 + k * 64 + mf * 16 + (l & 15)] = acc[kf][mf][q];
            if ((l & 15) == 0) Ksc[(size_t)g * KDIM + k] = acc[kf][4][q];
        }
    }
}

// ---------------- Kernel 3: exclusive prefix over chunks (f32, batched) ----------------
__global__ void k_scan(const float* __restrict__ KVc, const float* __restrict__ Ksc,
                       float* __restrict__ Sst, float* __restrict__ Kss)
{
    const int b = blockIdx.x / 65;
    const int r = blockIdx.x % 65;
    const int t = threadIdx.x;
    float acc = 0.f;
    if (r < 64) {
        const int e = r * 64 + t;
        for (int c0 = 0; c0 < NCHUNK; c0 += 8) {
            float v[8];
#pragma unroll
            for (int i = 0; i < 8; ++i)
                v[i] = KVc[((size_t)(b * NCHUNK + c0 + i)) * 4096 + e];
#pragma unroll
            for (int i = 0; i < 8; ++i) {
                Sst[((size_t)(b * NCHUNK + c0 + i)) * 4096 + e] = acc;
                acc += v[i];
            }
        }
    } else {
        for (int c0 = 0; c0 < NCHUNK; c0 += 8) {
            float v[8];
#pragma unroll
            for (int i = 0; i < 8; ++i)
                v[i] = Ksc[((size_t)(b * NCHUNK + c0 + i)) * KDIM + t];
#pragma unroll
            for (int i = 0; i < 8; ++i) {
                Kss[((size_t)(b * NCHUNK + c0 + i)) * KDIM + t] = acc;
                acc += v[i];
            }
        }
    }
}

// ---------------- Kernel 4: intra-chunk attention + output projection (fused) ----------------
// Per chunk g (grid 256, 4 waves): S=Q·Kf^T -> mask -> P(bf16 LDS, XOR-swz);
// num/den in one acc via ext-col MFMAs: P·[V|1] + Q·[SstT|Ksum]; O -> LDS frags;
// out = O·Wo^T (wave w owns cols w*256..+255), direct global write.
__global__ __launch_bounds__(256) void k_intra(
    const ushort* __restrict__ Qf, const ushort* __restrict__ Kff,
    const ushort* __restrict__ VT, const float* __restrict__ Sst,
    const float* __restrict__ Kss, const ushort* __restrict__ Wof,
    float* __restrict__ out)
{
    __shared__ ushort pb[64 * 64];   // P, then O-frags (XOR-swz by row)
    __shared__ ushort sT[80 * 64];   // SstT (rows 0-63 = m), row 64 = Ksum, 65-79 = 0
    const int g = blockIdx.x, t = threadIdx.x;
    const int w = t >> 6, l = t & 63;
    const int lq = l >> 4;

    // ---- build sT from f32 Sst (+ Ksum ext row) ----
    {
        const int k = t >> 2, m0 = (t & 3) * 16;
        const float4* sp = (const float4*)&Sst[(size_t)g * 4096 + k * 64 + m0];
        float4 f0 = sp[0], f1 = sp[1], f2v = sp[2], f3 = sp[3];
        float fv[16] = {f0.x, f0.y, f0.z, f0.w, f1.x, f1.y, f1.z, f1.w,
                        f2v.x, f2v.y, f2v.z, f2v.w, f3.x, f3.y, f3.z, f3.w};
#pragma unroll
        for (int i = 0; i < 16; ++i) {
            const int m = m0 + i;
            sT[m * 64 + (k ^ ((m & 7) << 3))] = f2bf(fv[i]);
        }
        if (t < 64) sT[64 * 64 + t] = f2bf(Kss[(size_t)g * KDIM + t]);
        for (int idx = t; idx < 960; idx += 256) sT[65 * 64 + idx] = 0;
    }

    // ---- S = Q·Kf^T (wave w: rows w*16..+15) ----
    short8v qa[2], kb[4][2];
    {
        const int mb = g * 2 + (w >> 1), rf = w & 1;
#pragma unroll
        for (int ks = 0; ks < 2; ++ks)
            qa[ks] = *(const short8v*)&Qf[((size_t)(mb * 4 + rf * 2 + ks)) * 512 + l * 8];
#pragma unroll
        for (int cf = 0; cf < 4; ++cf)
#pragma unroll
            for (int ks = 0; ks < 2; ++ks)
                kb[cf][ks] = *(const short8v*)&Kff[((size_t)((g * 2 + (cf >> 1)) * 4 + (cf & 1) * 2 + ks)) * 512 + l * 8];
    }
    f32x4 accs[4];
#pragma unroll
    for (int cf = 0; cf < 4; ++cf) accs[cf] = (f32x4){0.f, 0.f, 0.f, 0.f};
#pragma unroll
    for (int ks = 0; ks < 2; ++ks)
#pragma unroll
        for (int cf = 0; cf < 4; ++cf)
            accs[cf] = MFMA16(qa[ks], kb[cf][ks], accs[cf], 0, 0, 0);
    // mask + write P (own rows only)
#pragma unroll
    for (int cf = 0; cf < 4; ++cf)
#pragma unroll
        for (int q = 0; q < 4; ++q) {
            const int row = w * 16 + lq * 4 + q;
            const int col = cf * 16 + (l & 15);
            const float sv = (col <= row) ? accs[cf][q] : 0.f;
            pb[row * 64 + (col ^ ((row & 7) << 3))] = f2bf(sv);
        }
    __syncthreads();

    // ---- num/den: acc[0..3]=num cols, acc[4] col64 = den ----
    f32x4 accn[5];
#pragma unroll
    for (int mf = 0; mf < 5; ++mf) accn[mf] = (f32x4){0.f, 0.f, 0.f, 0.f};
    short8v onesf;
#pragma unroll
    for (int e = 0; e < 8; ++e) onesf[e] = ((l & 15) == 0) ? (short)0x3F80 : (short)0;
#pragma unroll
    for (int js = 0; js < 2; ++js) {
        const int prow = w * 16 + (l & 15);
        const int pbase = js * 32 + ((l >> 4) & 3) * 8;
        short8v pa = *(const short8v*)&pb[prow * 64 + (pbase ^ ((prow & 7) << 3))];
#pragma unroll
        for (int mf = 0; mf < 4; ++mf) {
            short8v vb = *(const short8v*)&VT[((size_t)(g * 8 + mf * 2 + js)) * 512 + l * 8];
            accn[mf] = MFMA16(pa, vb, accn[mf], 0, 0, 0);
        }
        accn[4] = MFMA16(pa, onesf, accn[4], 0, 0, 0);
    }
#pragma unroll
    for (int ks = 0; ks < 2; ++ks) {
        const int base = ks * 32 + ((l >> 4) & 3) * 8;
#pragma unroll
        for (int mf = 0; mf < 5; ++mf) {
            const int row = mf * 16 + (l & 15);
            short8v sb = *(const short8v*)&sT[row * 64 + (base ^ ((row & 7) << 3))];
            accn[mf] = MFMA16(qa[ks], sb, accn[mf], 0, 0, 0);
        }
    }
    // ---- O = num/(den+1e-6) -> pb (own rows) ----
#pragma unroll
    for (int q = 0; q < 4; ++q) {
        const float den = __shfl(accn[4][q], (l & 48));
        const float rinv = 1.f / (den + 1e-6f);
        const int row = w * 16 + lq * 4 + q;
#pragma unroll
        for (int mf = 0; mf < 4; ++mf) {
            const int col = mf * 16 + (l & 15);
            pb[row * 64 + (col ^ ((row & 7) << 3))] = f2bf(accn[mf][q] * rinv);
        }
    }
    __syncthreads();

    // ---- out = O·Wo^T (wave w: out cols w*256..+255) ----
    short8v oa[4][2];
#pragma unroll
    for (int rf = 0; rf < 4; ++rf)
#pragma unroll
        for (int ks = 0; ks < 2; ++ks) {
            const int row = rf * 16 + (l & 15);
            const int base = ks * 32 + ((l >> 4) & 3) * 8;
            oa[rf][ks] = *(const short8v*)&pb[row * 64 + (base ^ ((row & 7) << 3))];
        }
#pragma unroll
    for (int rr = 0; rr < 4; ++rr) {
        f32x4 acco[4][4];
#pragma unroll
        for (int rf = 0; rf < 4; ++rf)
#pragma unroll
            for (int ci = 0; ci < 4; ++ci) acco[rf][ci] = (f32x4){0.f, 0.f, 0.f, 0.f};
#pragma unroll
        for (int ci = 0; ci < 4; ++ci) {
            const int cfg = w * 16 + rr * 4 + ci;
#pragma unroll
            for (int ks = 0; ks < 2; ++ks) {
                short8v wb = *(const short8v*)&Wof[((size_t)(cfg * 2 + ks)) * 512 + l * 8];
#pragma unroll
                for (int rf = 0; rf < 4; ++rf)
                    acco[rf][ci] = MFMA16(oa[rf][ks], wb, acco[rf][ci], 0, 0, 0);
            }
        }
#pragma unroll
        for (int rf = 0; rf < 4; ++rf)
#pragma unroll
            for (int ci = 0; ci < 4; ++ci)
#pragma unroll
                for (int q = 0; q < 4; ++q)
                    out[((size_t)(g * 64 + rf * 16 + lq * 4 + q)) * DDIM
                        + w * 256 + rr * 64 + ci * 16 + (l & 15)] = acco[rf][ci][q];
    }
}

extern "C" void kernel_launch(void* const* d_in, const int* in_sizes, int n_in,
                              void* d_out, int out_size, void* d_ws, size_t ws_size,
                              hipStream_t stream)
{
    const float* x  = (const float*)d_in[0];
    const float* Wq = (const float*)d_in[1];
    const float* Wk = (const float*)d_in[2];
    const float* Wv = (const float*)d_in[3];
    const float* Wo = (const float*)d_in[4];
    float* out = (float*)d_out;

    float* ws   = (float*)d_ws;
    float* KVc  = ws;                                  // 256*4096 f32
    float* Sst  = KVc + (size_t)TCHUNK * 4096;         // 256*4096 f32
    float* Ksc  = Sst + (size_t)TCHUNK * 4096;         // 256*64 f32
    float* Kss  = Ksc + (size_t)TCHUNK * KDIM;         // 256*64 f32
    ushort* Whf = (ushort*)(Kss + (size_t)TCHUNK * KDIM);  // 192*1024
    ushort* Wof = Whf + (size_t)192 * DDIM;                // 64*1024
    ushort* Qf  = Wof + (size_t)64 * 1024;                 // 512*4*512
    ushort* Kff = Qf  + (size_t)512 * 4 * 512;
    ushort* KfT = Kff + (size_t)512 * 4 * 512;
    ushort* VT  = KfT + (size_t)256 * 8 * 512;

    k_wconv<<<dim3(256), dim3(256), 0, stream>>>(Wq, Wk, Wv, Wo, Whf, Wof);
    k_proj<<<dim3(MROWS / 32), dim3(256), 0, stream>>>(x, Whf, Qf, Kff, KfT, VT);
    k_chunksum<<<dim3(TCHUNK), dim3(64), 0, stream>>>(KfT, VT, KVc, Ksc);
    k_scan<<<dim3(BB * 65), dim3(64), 0, stream>>>(KVc, Ksc, Sst, Kss);
    k_intra<<<dim3(TCHUNK), dim3(256), 0, stream>>>(Qf, Kff, VT, Sst, Kss, Wof, out);
}

// Round 7
// 58.007 us; speedup vs baseline: 1.5549x; 1.1044x over previous
//
#include <hip/hip_runtime.h>

#define BB 4
#define SS 4096
#define DDIM 1024
#define KDIM 64
#define NCHUNK 64          // SS / CHUNK
#define TCHUNK 256         // BB * NCHUNK
#define MROWS 16384        // BB * SS

typedef short short8v __attribute__((ext_vector_type(8)));
typedef float f32x4 __attribute__((ext_vector_type(4)));
#define MFMA16 __builtin_amdgcn_mfma_f32_16x16x32_bf16

__device__ __forceinline__ ushort f2bf(float f) {
    uint u = __float_as_uint(f);
    u += 0x7FFFu + ((u >> 16) & 1u);
    return (ushort)(u >> 16);
}

// ---------------- Kernel 0: weight conversion + fragment packing ----------------
__global__ __launch_bounds__(256) void k_wconv(
    const float* __restrict__ Wq, const float* __restrict__ Wk,
    const float* __restrict__ Wv, const float* __restrict__ Wo,
    ushort* __restrict__ Whf, ushort* __restrict__ Wof)
{
    const int b = blockIdx.x, t = threadIdx.x;
    const int ks = t >> 7;            // 0..1
    const int l = (t >> 1) & 63;      // lane
    const int half = t & 1;           // low/high 4 elems
    if (b < 192) {
        const int s = b / 12, cf = b % 12;
        const int grow = cf * 16 + (l & 15);
        const int gcol = s * 64 + ks * 32 + ((l >> 4) & 3) * 8 + half * 4;
        const float* src = (grow < 64) ? (Wq + (size_t)grow * DDIM)
                         : (grow < 128) ? (Wk + (size_t)(grow - 64) * DDIM)
                                        : (Wv + (size_t)(grow - 128) * DDIM);
        float4 v = *(const float4*)&src[gcol];
        ushort* dst = &Whf[(size_t)(((s * 12 + cf) * 2 + ks) * 64 + l) * 8 + half * 4];
        dst[0] = f2bf(v.x); dst[1] = f2bf(v.y); dst[2] = f2bf(v.z); dst[3] = f2bf(v.w);
    } else {
        const int cf = b - 192;           // 0..63
        const int d = cf * 16 + (l & 15);
        const int kc = ks * 32 + ((l >> 4) & 3) * 8 + half * 4;
        float4 v = *(const float4*)&Wo[(size_t)d * KDIM + kc];
        ushort* dst = &Wof[(size_t)((cf * 2 + ks) * 64 + l) * 8 + half * 4];
        dst[0] = f2bf(v.x); dst[1] = f2bf(v.y); dst[2] = f2bf(v.z); dst[3] = f2bf(v.w);
    }
}

// ---------------- Kernel 1: fused QKV projection -> frag-packed bf16 ----------------
// BM=32, grid=512, 4 waves. xs = 32KB (one K-half) -> 4-5 blocks/CU.
// Staging: wave reads 2KB contiguous per instr; ds_write slot XOR-swizzled (frag&7).
// W streamed global->reg (frag-packed, coalesced), barrier-free inside each half.
#define EBP 216   // epilogue buffer row pitch (ushorts)
__global__ __launch_bounds__(256) void k_proj(
    const float* __restrict__ x, const ushort* __restrict__ Whf,
    ushort* __restrict__ Qf, ushort* __restrict__ Kff,
    ushort* __restrict__ KfT, ushort* __restrict__ VT)
{
    __shared__ ushort xs[32 * 512];   // 32 KB: frags (rf*16 + kkl), kkl = K/32 in half
    const int t = threadIdx.x;
    const int w = t >> 6, l = t & 63;
    const int mb = blockIdx.x;
    const int row0 = mb * 32;

    f32x4 acc[2][3];
#pragma unroll
    for (int r = 0; r < 2; ++r)
#pragma unroll
        for (int c = 0; c < 3; ++c) acc[r][c] = (f32x4){0.f, 0.f, 0.f, 0.f};

    // stage rows 0..31 x cols [h*512, h*512+512): flat float8 idx = i*256+t
    // -> row = idx>>6 (wave-uniform), col = (idx&63)*8 (lane*8 contiguous)
    auto stageX = [&](int h) {
#pragma unroll
        for (int i = 0; i < 8; ++i) {
            const int fidx = i * 256 + t;
            const int r = fidx >> 6;
            const int c = (fidx & 63) * 8;
            const float* p = &x[(size_t)(row0 + r) * DDIM + h * 512 + c];
            float4 u0 = *(const float4*)p;
            float4 u1 = *(const float4*)(p + 4);
            short8v hh;
            hh[0] = (short)f2bf(u0.x); hh[1] = (short)f2bf(u0.y);
            hh[2] = (short)f2bf(u0.z); hh[3] = (short)f2bf(u0.w);
            hh[4] = (short)f2bf(u1.x); hh[5] = (short)f2bf(u1.y);
            hh[6] = (short)f2bf(u1.z); hh[7] = (short)f2bf(u1.w);
            const int frag = (r >> 4) * 16 + (c >> 5);
            const int slot = ((r & 15) | (((c >> 3) & 3) << 4)) ^ (frag & 7);
            *(short8v*)&xs[(size_t)(frag * 64 + slot) * 8] = hh;
        }
    };
    auto loadW = [&](int sg, short8v (&bw)[6]) {
#pragma unroll
        for (int j = 0; j < 6; ++j) {
            const int cf = w * 3 + (j >> 1);
            const int f = cf * 2 + (j & 1);
            bw[j] = *(const short8v*)&Whf[((size_t)(sg * 24 + f)) * 512 + l * 8];
        }
    };
    auto computeStep = [&](int sl, short8v (&bw)[6]) {
#pragma unroll
        for (int ks = 0; ks < 2; ++ks) {
            const int kkl = sl * 2 + ks;
            const int f0 = kkl, f1 = 16 + kkl;
            short8v a0 = *(const short8v*)&xs[(size_t)(f0 * 64 + (l ^ (f0 & 7))) * 8];
            short8v a1 = *(const short8v*)&xs[(size_t)(f1 * 64 + (l ^ (f1 & 7))) * 8];
#pragma unroll
            for (int c = 0; c < 3; ++c) {
                acc[0][c] = MFMA16(a0, bw[c * 2 + ks], acc[0][c], 0, 0, 0);
                acc[1][c] = MFMA16(a1, bw[c * 2 + ks], acc[1][c], 0, 0, 0);
            }
        }
    };

    for (int h = 0; h < 2; ++h) {
        if (h) __syncthreads();          // prev half's compute done
        stageX(h);
        __syncthreads();                 // xs ready
        short8v bwA[6], bwB[6];
        loadW(h * 8, bwA);
        for (int s = 0; s < 8; s += 2) {
            loadW(h * 8 + s + 1, bwB);
            computeStep(s, bwA);
            if (s + 2 < 8) loadW(h * 8 + s + 2, bwA);
            computeStep(s + 1, bwB);
        }
    }

    // ---- epilogue: C-layout -> eb[32][EBP] (elu+1 on cols<128) ----
    __syncthreads();
    ushort* eb = xs;
#pragma unroll
    for (int rf = 0; rf < 2; ++rf)
#pragma unroll
        for (int c = 0; c < 3; ++c) {
            const int col = w * 48 + c * 16 + (l & 15);
#pragma unroll
            for (int q = 0; q < 4; ++q) {
                const int rl = rf * 16 + ((l >> 4) << 2) + q;
                float v = acc[rf][c][q];
                if (col < 128) v = (v > 0.f) ? v + 1.f : __expf(v);  // elu+1
                eb[rl * EBP + col] = f2bf(v);
            }
        }
    __syncthreads();

    // ---- row-frag stores: Qf/Kff [mb][rf2][ks2] ----
    {
        const int rf = t >> 7, ks = (t >> 6) & 1, lam = t & 63;
        const int r = rf * 16 + (lam & 15);
        const int c0 = ks * 32 + ((lam >> 4) & 3) * 8;
        short8v q8 = *(const short8v*)&eb[r * EBP + c0];
        short8v k8 = *(const short8v*)&eb[r * EBP + 64 + c0];
        const size_t fo = ((size_t)(mb * 4 + rf * 2 + ks)) * 512 + lam * 8;
        *(short8v*)&Qf[fo] = q8;
        *(short8v*)&Kff[fo] = k8;
    }
    // ---- T-frag stores: KfT/VT [g][f4][js2], g=mb>>1, js=mb&1 ----
    {
        const int f = t >> 6, lam = t & 63;
        const int kcol = 64 + f * 16 + (lam & 15);
        const int vcol = 128 + f * 16 + (lam & 15);
        const int jb = ((lam >> 4) & 3) * 8;
        short8v kT, vT;
#pragma unroll
        for (int e = 0; e < 8; ++e) {
            kT[e] = (short)eb[(jb + e) * EBP + kcol];
            vT[e] = (short)eb[(jb + e) * EBP + vcol];
        }
        const size_t fo = ((size_t)((mb >> 1) * 8 + f * 2 + (mb & 1))) * 512 + lam * 8;
        *(short8v*)&KfT[fo] = kT;
        *(short8v*)&VT[fo] = vT;
    }
}

// ---------------- Kernel 2: per-chunk KV summary (MFMA, 1 wave/block) ----------------
__global__ __launch_bounds__(64) void k_chunksum(
    const ushort* __restrict__ KfT, const ushort* __restrict__ VT,
    float* __restrict__ KVc, float* __restrict__ Ksc)
{
    const int g = blockIdx.x, l = threadIdx.x;
    short8v ka[4][2], vb[4][2];
#pragma unroll
    for (int f = 0; f < 4; ++f)
#pragma unroll
        for (int js = 0; js < 2; ++js) {
            const size_t fo = ((size_t)(g * 8 + f * 2 + js)) * 512 + l * 8;
            ka[f][js] = *(const short8v*)&KfT[fo];
            vb[f][js] = *(const short8v*)&VT[fo];
        }
    short8v onesf;
#pragma unroll
    for (int e = 0; e < 8; ++e) onesf[e] = ((l & 15) == 0) ? (short)0x3F80 : (short)0;

    f32x4 acc[4][5];
#pragma unroll
    for (int kf = 0; kf < 4; ++kf)
#pragma unroll
        for (int mf = 0; mf < 5; ++mf) acc[kf][mf] = (f32x4){0.f, 0.f, 0.f, 0.f};
#pragma unroll
    for (int js = 0; js < 2; ++js)
#pragma unroll
        for (int kf = 0; kf < 4; ++kf) {
#pragma unroll
            for (int mf = 0; mf < 4; ++mf)
                acc[kf][mf] = MFMA16(ka[kf][js], vb[mf][js], acc[kf][mf], 0, 0, 0);
            acc[kf][4] = MFMA16(ka[kf][js], onesf, acc[kf][4], 0, 0, 0);
        }
    const int lq = l >> 4;
#pragma unroll
    for (int kf = 0; kf < 4; ++kf) {
#pragma unroll
        for (int q = 0; q < 4; ++q) {
            const int k = kf * 16 + lq * 4 + q;
#pragma unroll
            for (int mf = 0; mf < 4; ++mf)
                KVc[(size_t)g * 4096 + k * 64 + mf * 16 + (l & 15)] = acc[kf][mf][q];
            if ((l & 15) == 0) Ksc[(size_t)g * KDIM + k] = acc[kf][4][q];
        }
    }
}

// ---------------- Kernel 3: exclusive prefix over chunks (all-register) ----------------
__global__ void k_scan(const float* __restrict__ KVc, const float* __restrict__ Ksc,
                       float* __restrict__ Sst, float* __restrict__ Kss)
{
    const int b = blockIdx.x / 65;
    const int r = blockIdx.x % 65;
    const int t = threadIdx.x;
    if (r < 64) {
        const int e = r * 64 + t;
        float v[64];
#pragma unroll
        for (int i = 0; i < 64; ++i)
            v[i] = KVc[((size_t)(b * NCHUNK + i)) * 4096 + e];
        float acc = 0.f;
#pragma unroll
        for (int i = 0; i < 64; ++i) {
            Sst[((size_t)(b * NCHUNK + i)) * 4096 + e] = acc;
            acc += v[i];
        }
    } else {
        float v[64];
#pragma unroll
        for (int i = 0; i < 64; ++i)
            v[i] = Ksc[((size_t)(b * NCHUNK + i)) * KDIM + t];
        float acc = 0.f;
#pragma unroll
        for (int i = 0; i < 64; ++i) {
            Kss[((size_t)(b * NCHUNK + i)) * KDIM + t] = acc;
            acc += v[i];
        }
    }
}

// ---------------- Kernel 4: intra-chunk attention + output projection (fused) ----------------
__global__ __launch_bounds__(256) void k_intra(
    const ushort* __restrict__ Qf, const ushort* __restrict__ Kff,
    const ushort* __restrict__ VT, const float* __restrict__ Sst,
    const float* __restrict__ Kss, const ushort* __restrict__ Wof,
    float* __restrict__ out)
{
    __shared__ ushort pb[64 * 64];   // P, then O-frags (XOR-swz by row)
    __shared__ ushort sT[80 * 64];   // SstT (rows 0-63 = m), row 64 = Ksum, 65-79 = 0
    __shared__ float ob[4][16 * 68 + 4];  // per-wave f32 store-transpose tile
    const int g = blockIdx.x, t = threadIdx.x;
    const int w = t >> 6, l = t & 63;
    const int lq = l >> 4;

    // ---- build sT from f32 Sst (+ Ksum ext row) ----
    {
        const int k = t >> 2, m0 = (t & 3) * 16;
        const float4* sp = (const float4*)&Sst[(size_t)g * 4096 + k * 64 + m0];
        float4 f0 = sp[0], f1 = sp[1], f2v = sp[2], f3 = sp[3];
        float fv[16] = {f0.x, f0.y, f0.z, f0.w, f1.x, f1.y, f1.z, f1.w,
                        f2v.x, f2v.y, f2v.z, f2v.w, f3.x, f3.y, f3.z, f3.w};
#pragma unroll
        for (int i = 0; i < 16; ++i) {
            const int m = m0 + i;
            sT[m * 64 + (k ^ ((m & 7) << 3))] = f2bf(fv[i]);
        }
        if (t < 64) sT[64 * 64 + t] = f2bf(Kss[(size_t)g * KDIM + t]);
        for (int idx = t; idx < 960; idx += 256) sT[65 * 64 + idx] = 0;
    }

    // ---- S = Q·Kf^T (wave w: rows w*16..+15) ----
    short8v qa[2], kb[4][2];
    {
        const int mb = g * 2 + (w >> 1), rf = w & 1;
#pragma unroll
        for (int ks = 0; ks < 2; ++ks)
            qa[ks] = *(const short8v*)&Qf[((size_t)(mb * 4 + rf * 2 + ks)) * 512 + l * 8];
#pragma unroll
        for (int cf = 0; cf < 4; ++cf)
#pragma unroll
            for (int ks = 0; ks < 2; ++ks)
                kb[cf][ks] = *(const short8v*)&Kff[((size_t)((g * 2 + (cf >> 1)) * 4 + (cf & 1) * 2 + ks)) * 512 + l * 8];
    }
    f32x4 accs[4];
#pragma unroll
    for (int cf = 0; cf < 4; ++cf) accs[cf] = (f32x4){0.f, 0.f, 0.f, 0.f};
#pragma unroll
    for (int ks = 0; ks < 2; ++ks)
#pragma unroll
        for (int cf = 0; cf < 4; ++cf)
            accs[cf] = MFMA16(qa[ks], kb[cf][ks], accs[cf], 0, 0, 0);
#pragma unroll
    for (int cf = 0; cf < 4; ++cf)
#pragma unroll
        for (int q = 0; q < 4; ++q) {
            const int row = w * 16 + lq * 4 + q;
            const int col = cf * 16 + (l & 15);
            const float sv = (col <= row) ? accs[cf][q] : 0.f;
            pb[row * 64 + (col ^ ((row & 7) << 3))] = f2bf(sv);
        }
    __syncthreads();

    // ---- num/den: acc[0..3]=num cols, acc[4] col64 = den ----
    f32x4 accn[5];
#pragma unroll
    for (int mf = 0; mf < 5; ++mf) accn[mf] = (f32x4){0.f, 0.f, 0.f, 0.f};
    short8v onesf;
#pragma unroll
    for (int e = 0; e < 8; ++e) onesf[e] = ((l & 15) == 0) ? (short)0x3F80 : (short)0;
#pragma unroll
    for (int js = 0; js < 2; ++js) {
        const int prow = w * 16 + (l & 15);
        const int pbase = js * 32 + ((l >> 4) & 3) * 8;
        short8v pa = *(const short8v*)&pb[prow * 64 + (pbase ^ ((prow & 7) << 3))];
#pragma unroll
        for (int mf = 0; mf < 4; ++mf) {
            short8v vb = *(const short8v*)&VT[((size_t)(g * 8 + mf * 2 + js)) * 512 + l * 8];
            accn[mf] = MFMA16(pa, vb, accn[mf], 0, 0, 0);
        }
        accn[4] = MFMA16(pa, onesf, accn[4], 0, 0, 0);
    }
#pragma unroll
    for (int ks = 0; ks < 2; ++ks) {
        const int base = ks * 32 + ((l >> 4) & 3) * 8;
#pragma unroll
        for (int mf = 0; mf < 5; ++mf) {
            const int row = mf * 16 + (l & 15);
            short8v sb = *(const short8v*)&sT[row * 64 + (base ^ ((row & 7) << 3))];
            accn[mf] = MFMA16(qa[ks], sb, accn[mf], 0, 0, 0);
        }
    }
    // ---- O = num/(den+1e-6) -> pb (own rows) ----
#pragma unroll
    for (int q = 0; q < 4; ++q) {
        const float den = __shfl(accn[4][q], (l & 48));
        const float rinv = 1.f / (den + 1e-6f);
        const int row = w * 16 + lq * 4 + q;
#pragma unroll
        for (int mf = 0; mf < 4; ++mf) {
            const int col = mf * 16 + (l & 15);
            pb[row * 64 + (col ^ ((row & 7) << 3))] = f2bf(accn[mf][q] * rinv);
        }
    }
    __syncthreads();

    // ---- out = O·Wo^T (wave w: out cols w*256..+255), float4 stores via ob ----
    short8v oa[4][2];
#pragma unroll
    for (int rf = 0; rf < 4; ++rf)
#pragma unroll
        for (int ks = 0; ks < 2; ++ks) {
            const int row = rf * 16 + (l & 15);
            const int base = ks * 32 + ((l >> 4) & 3) * 8;
            oa[rf][ks] = *(const short8v*)&pb[row * 64 + (base ^ ((row & 7) << 3))];
        }
    float* obw = ob[w];
#pragma unroll
    for (int rr = 0; rr < 4; ++rr) {
        f32x4 acco[4][4];
#pragma unroll
        for (int rf = 0; rf < 4; ++rf)
#pragma unroll
            for (int ci = 0; ci < 4; ++ci) acco[rf][ci] = (f32x4){0.f, 0.f, 0.f, 0.f};
#pragma unroll
        for (int ci = 0; ci < 4; ++ci) {
            const int cfg = w * 16 + rr * 4 + ci;
#pragma unroll
            for (int ks = 0; ks < 2; ++ks) {
                short8v wb = *(const short8v*)&Wof[((size_t)(cfg * 2 + ks)) * 512 + l * 8];
#pragma unroll
                for (int rf = 0; rf < 4; ++rf)
                    acco[rf][ci] = MFMA16(oa[rf][ks], wb, acco[rf][ci], 0, 0, 0);
            }
        }
#pragma unroll
        for (int rf = 0; rf < 4; ++rf) {
            // acco -> per-wave LDS tile (pitch 68)
#pragma unroll
            for (int ci = 0; ci < 4; ++ci)
#pragma unroll
                for (int q = 0; q < 4; ++q)
                    obw[(lq * 4 + q) * 68 + ci * 16 + (l & 15)] = acco[rf][ci][q];
            // read back float4, store 256B-contiguous per 16 lanes
#pragma unroll
            for (int rg = 0; rg < 4; ++rg) {
                const int row = rg * 4 + lq;
                float4 vv = *(const float4*)&obw[row * 68 + (l & 15) * 4];
                *(float4*)&out[((size_t)(g * 64 + rf * 16 + row)) * DDIM
                               + w * 256 + rr * 64 + (l & 15) * 4] = vv;
            }
        }
    }
}

extern "C" void kernel_launch(void* const* d_in, const int* in_sizes, int n_in,
                              void* d_out, int out_size, void* d_ws, size_t ws_size,
                              hipStream_t stream)
{
    const float* x  = (const float*)d_in[0];
    const float* Wq = (const float*)d_in[1];
    const float* Wk = (const float*)d_in[2];
    const float* Wv = (const float*)d_in[3];
    const float* Wo = (const float*)d_in[4];
    float* out = (float*)d_out;

    float* ws   = (float*)d_ws;
    float* KVc  = ws;                                  // 256*4096 f32
    float* Sst  = KVc + (size_t)TCHUNK * 4096;         // 256*4096 f32
    float* Ksc  = Sst + (size_t)TCHUNK * 4096;         // 256*64 f32
    float* Kss  = Ksc + (size_t)TCHUNK * KDIM;         // 256*64 f32
    ushort* Whf = (ushort*)(Kss + (size_t)TCHUNK * KDIM);  // 192*1024
    ushort* Wof = Whf + (size_t)192 * DDIM;                // 64*1024
    ushort* Qf  = Wof + (size_t)64 * 1024;                 // 512*4*512
    ushort* Kff = Qf  + (size_t)512 * 4 * 512;
    ushort* KfT = Kff + (size_t)512 * 4 * 512;
    ushort* VT  = KfT + (size_t)256 * 8 * 512;

    k_wconv<<<dim3(256), dim3(256), 0, stream>>>(Wq, Wk, Wv, Wo, Whf, Wof);
    k_proj<<<dim3(MROWS / 32), dim3(256), 0, stream>>>(x, Whf, Qf, Kff, KfT, VT);
    k_chunksum<<<dim3(TCHUNK), dim3(64), 0, stream>>>(KfT, VT, KVc, Ksc);
    k_scan<<<dim3(BB * 65), dim3(64), 0, stream>>>(KVc, Ksc, Sst, Kss);
    k_intra<<<dim3(TCHUNK), dim3(256), 0, stream>>>(Qf, Kff, VT, Sst, Kss, Wof, out);
}

// Round 8
// 56.804 us; speedup vs baseline: 1.5878x; 1.0212x over previous
//
#include <hip/hip_runtime.h>

#define BB 4
#define SS 4096
#define DDIM 1024
#define KDIM 64
#define NCHUNK 64          // SS / CHUNK
#define TCHUNK 256         // BB * NCHUNK
#define MROWS 16384        // BB * SS

typedef short short8v __attribute__((ext_vector_type(8)));
typedef float f32x4 __attribute__((ext_vector_type(4)));
#define MFMA16 __builtin_amdgcn_mfma_f32_16x16x32_bf16

__device__ __forceinline__ ushort f2bf(float f) {
    uint u = __float_as_uint(f);
    u += 0x7FFFu + ((u >> 16) & 1u);
    return (ushort)(u >> 16);
}

// ---------------- Kernel 0: weight conversion + fragment packing ----------------
__global__ __launch_bounds__(256) void k_wconv(
    const float* __restrict__ Wq, const float* __restrict__ Wk,
    const float* __restrict__ Wv, const float* __restrict__ Wo,
    ushort* __restrict__ Whf, ushort* __restrict__ Wof)
{
    const int b = blockIdx.x, t = threadIdx.x;
    const int ks = t >> 7;            // 0..1
    const int l = (t >> 1) & 63;      // lane
    const int half = t & 1;           // low/high 4 elems
    if (b < 192) {
        const int s = b / 12, cf = b % 12;
        const int grow = cf * 16 + (l & 15);
        const int gcol = s * 64 + ks * 32 + ((l >> 4) & 3) * 8 + half * 4;
        const float* src = (grow < 64) ? (Wq + (size_t)grow * DDIM)
                         : (grow < 128) ? (Wk + (size_t)(grow - 64) * DDIM)
                                        : (Wv + (size_t)(grow - 128) * DDIM);
        float4 v = *(const float4*)&src[gcol];
        ushort* dst = &Whf[(size_t)(((s * 12 + cf) * 2 + ks) * 64 + l) * 8 + half * 4];
        dst[0] = f2bf(v.x); dst[1] = f2bf(v.y); dst[2] = f2bf(v.z); dst[3] = f2bf(v.w);
    } else {
        const int cf = b - 192;           // 0..63
        const int d = cf * 16 + (l & 15);
        const int kc = ks * 32 + ((l >> 4) & 3) * 8 + half * 4;
        float4 v = *(const float4*)&Wo[(size_t)d * KDIM + kc];
        ushort* dst = &Wof[(size_t)((cf * 2 + ks) * 64 + l) * 8 + half * 4];
        dst[0] = f2bf(v.x); dst[1] = f2bf(v.y); dst[2] = f2bf(v.z); dst[3] = f2bf(v.w);
    }
}

// ---------------- Kernel 1: fused QKV projection + per-chunk KV summary ----------------
// BM=64 (= one chunk), 512 threads (8 waves: rw=w>>2, cw=w&3), grid 256.
// x double-buffered (2x64KB), T14 issue-early/write-late staging. W reg-streamed.
// Epilogue: eb[64][EBP] -> Qf/Kff/VT frag stores + in-block chunksum (KVc,Ksc).
#define EBP 216
__global__ __launch_bounds__(512) void k_proj(
    const float* __restrict__ x, const ushort* __restrict__ Whf,
    ushort* __restrict__ Qf, ushort* __restrict__ Kff, ushort* __restrict__ VT,
    float* __restrict__ KVc, float* __restrict__ Ksc)
{
    __shared__ ushort xs[2 * 64 * 512];   // 128 KB: 2 bufs x 64 frags x 512
    const int t = threadIdx.x;
    const int w = t >> 6, l = t & 63;
    const int rw = w >> 2, cw = w & 3;
    const int g = blockIdx.x;
    const int row0 = g * 64;
    const int lq = l >> 4;

    float4 xr[16];
    auto stageLoad = [&](int h) {
#pragma unroll
        for (int i = 0; i < 8; ++i) {
            const int fidx = i * 512 + t;
            const int r = fidx >> 6;
            const int c = (fidx & 63) * 8;
            const float* p = &x[(size_t)(row0 + r) * DDIM + h * 512 + c];
            xr[i * 2] = *(const float4*)p;
            xr[i * 2 + 1] = *(const float4*)(p + 4);
        }
    };
    auto stageWrite = [&](int buf) {
        ushort* xb = xs + buf * 32768;
#pragma unroll
        for (int i = 0; i < 8; ++i) {
            const int fidx = i * 512 + t;
            const int r = fidx >> 6;
            const int c = (fidx & 63) * 8;
            float4 u0 = xr[i * 2], u1 = xr[i * 2 + 1];
            short8v hh;
            hh[0] = (short)f2bf(u0.x); hh[1] = (short)f2bf(u0.y);
            hh[2] = (short)f2bf(u0.z); hh[3] = (short)f2bf(u0.w);
            hh[4] = (short)f2bf(u1.x); hh[5] = (short)f2bf(u1.y);
            hh[6] = (short)f2bf(u1.z); hh[7] = (short)f2bf(u1.w);
            const int frag = (r >> 4) * 16 + (c >> 5);
            const int slot = ((r & 15) | (((c >> 3) & 3) << 4)) ^ (frag & 7);
            *(short8v*)&xb[(size_t)(frag * 64 + slot) * 8] = hh;
        }
    };

    f32x4 acc[2][3];
#pragma unroll
    for (int r = 0; r < 2; ++r)
#pragma unroll
        for (int c = 0; c < 3; ++c) acc[r][c] = (f32x4){0.f, 0.f, 0.f, 0.f};

    auto loadW = [&](int sg, short8v (&bw)[6]) {
#pragma unroll
        for (int j = 0; j < 6; ++j) {
            const int cf = cw * 3 + (j >> 1);
            const int f = cf * 2 + (j & 1);
            bw[j] = *(const short8v*)&Whf[((size_t)(sg * 24 + f)) * 512 + l * 8];
        }
    };
    auto computeStep = [&](int buf, int sl, short8v (&bw)[6]) {
        const ushort* xb = xs + buf * 32768;
#pragma unroll
        for (int ks = 0; ks < 2; ++ks) {
            const int kkl = sl * 2 + ks;
            const int f0 = (rw * 2) * 16 + kkl;
            const int f1 = (rw * 2 + 1) * 16 + kkl;
            short8v a0 = *(const short8v*)&xb[(size_t)(f0 * 64 + (l ^ (f0 & 7))) * 8];
            short8v a1 = *(const short8v*)&xb[(size_t)(f1 * 64 + (l ^ (f1 & 7))) * 8];
#pragma unroll
            for (int c = 0; c < 3; ++c) {
                acc[0][c] = MFMA16(a0, bw[c * 2 + ks], acc[0][c], 0, 0, 0);
                acc[1][c] = MFMA16(a1, bw[c * 2 + ks], acc[1][c], 0, 0, 0);
            }
        }
    };

    stageLoad(0); stageWrite(0);
    __syncthreads();
    stageLoad(1);                       // issue-early: HBM hides under compute(0)
    {
        short8v bwA[6], bwB[6];
        loadW(0, bwA);
        for (int s = 0; s < 8; s += 2) {
            loadW(s + 1, bwB);
            computeStep(0, s, bwA);
            if (s + 2 < 8) loadW(s + 2, bwA);
            computeStep(0, s + 1, bwB);
        }
    }
    stageWrite(1);                      // write-late
    __syncthreads();
    {
        short8v bwA[6], bwB[6];
        loadW(8, bwA);
        for (int s = 0; s < 8; s += 2) {
            loadW(8 + s + 1, bwB);
            computeStep(1, s, bwA);
            if (s + 2 < 8) loadW(8 + s + 2, bwA);
            computeStep(1, s + 1, bwB);
        }
    }

    // ---- epilogue: C-frags -> eb[64][EBP] (buf0 space; elu+1 on cols<128) ----
    ushort* eb = xs;
#pragma unroll
    for (int rfi = 0; rfi < 2; ++rfi)
#pragma unroll
        for (int ci = 0; ci < 3; ++ci) {
            const int col = (cw * 3 + ci) * 16 + (l & 15);
#pragma unroll
            for (int q = 0; q < 4; ++q) {
                const int rl = (rw * 2 + rfi) * 16 + lq * 4 + q;
                float v = acc[rfi][ci][q];
                if (col < 128) v = (v > 0.f) ? v + 1.f : __expf(v);  // elu+1
                eb[rl * EBP + col] = f2bf(v);
            }
        }
    __syncthreads();

    // ---- Qf/Kff row-frag stores (8 frags each, 512 threads) ----
    {
        const int fj = t >> 6, lam = t & 63;
        const int rh = fj >> 2, rfm = (fj >> 1) & 1, ks = fj & 1;
        const int r = rh * 32 + rfm * 16 + (lam & 15);
        const int c0 = ks * 32 + ((lam >> 4) & 3) * 8;
        short8v q8 = *(const short8v*)&eb[r * EBP + c0];
        short8v k8 = *(const short8v*)&eb[r * EBP + 64 + c0];
        const size_t fo = ((size_t)((g * 2 + rh) * 4 + rfm * 2 + ks)) * 512 + lam * 8;
        *(short8v*)&Qf[fo] = q8;
        *(short8v*)&Kff[fo] = k8;
    }
    // ---- VT T-frag stores ----
    {
        const int fj = t >> 6, lam = t & 63;
        const int f = fj >> 1, js = fj & 1;
        const int jb = js * 32 + ((lam >> 4) & 3) * 8;
        const int vcol = 128 + f * 16 + (lam & 15);
        short8v vT;
#pragma unroll
        for (int e = 0; e < 8; ++e) vT[e] = (short)eb[(jb + e) * EBP + vcol];
        *(short8v*)&VT[((size_t)(g * 8 + f * 2 + js)) * 512 + lam * 8] = vT;
    }
    // ---- in-block chunksum: KVc[g] = Kf^T V (+ones -> Ksc) ----
    {
        const int kf = w & 3, mh = w >> 2;
        short8v ka[2], vb0[2], vb1[2];
#pragma unroll
        for (int js = 0; js < 2; ++js) {
            const int jb = js * 32 + ((l >> 4) & 3) * 8;
#pragma unroll
            for (int e = 0; e < 8; ++e) {
                const int j = jb + e;
                ka[js][e]  = (short)eb[j * EBP + 64 + kf * 16 + (l & 15)];
                vb0[js][e] = (short)eb[j * EBP + 128 + (mh * 2 + 0) * 16 + (l & 15)];
                vb1[js][e] = (short)eb[j * EBP + 128 + (mh * 2 + 1) * 16 + (l & 15)];
            }
        }
        f32x4 a0 = (f32x4){0.f,0.f,0.f,0.f}, a1 = (f32x4){0.f,0.f,0.f,0.f};
        f32x4 ad = (f32x4){0.f,0.f,0.f,0.f};
        short8v onesf;
#pragma unroll
        for (int e = 0; e < 8; ++e) onesf[e] = ((l & 15) == 0) ? (short)0x3F80 : (short)0;
#pragma unroll
        for (int js = 0; js < 2; ++js) {
            a0 = MFMA16(ka[js], vb0[js], a0, 0, 0, 0);
            a1 = MFMA16(ka[js], vb1[js], a1, 0, 0, 0);
            if (mh == 0) ad = MFMA16(ka[js], onesf, ad, 0, 0, 0);
        }
#pragma unroll
        for (int q = 0; q < 4; ++q) {
            const int k = kf * 16 + lq * 4 + q;
            KVc[(size_t)g * 4096 + k * 64 + (mh * 2 + 0) * 16 + (l & 15)] = a0[q];
            KVc[(size_t)g * 4096 + k * 64 + (mh * 2 + 1) * 16 + (l & 15)] = a1[q];
            if (mh == 0 && (l & 15) == 0) Ksc[(size_t)g * KDIM + k] = ad[q];
        }
    }
}

// ---------------- Kernel 2: exclusive prefix over chunks (all-register) ----------------
__global__ void k_scan(const float* __restrict__ KVc, const float* __restrict__ Ksc,
                       float* __restrict__ Sst, float* __restrict__ Kss)
{
    const int b = blockIdx.x / 65;
    const int r = blockIdx.x % 65;
    const int t = threadIdx.x;
    if (r < 64) {
        const int e = r * 64 + t;
        float v[64];
#pragma unroll
        for (int i = 0; i < 64; ++i)
            v[i] = KVc[((size_t)(b * NCHUNK + i)) * 4096 + e];
        float acc = 0.f;
#pragma unroll
        for (int i = 0; i < 64; ++i) {
            Sst[((size_t)(b * NCHUNK + i)) * 4096 + e] = acc;
            acc += v[i];
        }
    } else {
        float v[64];
#pragma unroll
        for (int i = 0; i < 64; ++i)
            v[i] = Ksc[((size_t)(b * NCHUNK + i)) * KDIM + t];
        float acc = 0.f;
#pragma unroll
        for (int i = 0; i < 64; ++i) {
            Kss[((size_t)(b * NCHUNK + i)) * KDIM + t] = acc;
            acc += v[i];
        }
    }
}

// ---------------- Kernel 3: intra-chunk attention + output projection ----------------
// grid 512: block (g = bx>>1, rh = bx&1) handles rows rh*32..+31 of chunk g.
// 4 waves: S (rf=w&1, cfh=w>>1), PV/QS (rf=w&1, mg=w>>1), outproj (wave w: cols w*256).
__global__ __launch_bounds__(256) void k_intra(
    const ushort* __restrict__ Qf, const ushort* __restrict__ Kff,
    const ushort* __restrict__ VT, const float* __restrict__ Sst,
    const float* __restrict__ Kss, const ushort* __restrict__ Wof,
    float* __restrict__ out)
{
    __shared__ ushort pb[32 * 64];        // P / O tile (rows block-local, XOR-swz)
    __shared__ ushort sT[80 * 64];        // SstT rows 0..63, row 64 = Ksum, 65..79 = 0
    __shared__ float ob[4][16 * 68 + 4];  // per-wave f32 store-transpose tile
    const int bx = blockIdx.x, t = threadIdx.x;
    const int g = bx >> 1, rh = bx & 1;
    const int w = t >> 6, l = t & 63;
    const int lq = l >> 4;

    // ---- build sT from f32 Sst (+ Ksum ext row) ----
    {
        const int k = t >> 2, m0 = (t & 3) * 16;
        const float4* sp = (const float4*)&Sst[(size_t)g * 4096 + k * 64 + m0];
        float4 f0 = sp[0], f1 = sp[1], f2v = sp[2], f3 = sp[3];
        float fv[16] = {f0.x, f0.y, f0.z, f0.w, f1.x, f1.y, f1.z, f1.w,
                        f2v.x, f2v.y, f2v.z, f2v.w, f3.x, f3.y, f3.z, f3.w};
#pragma unroll
        for (int i = 0; i < 16; ++i) {
            const int m = m0 + i;
            sT[m * 64 + (k ^ ((m & 7) << 3))] = f2bf(fv[i]);
        }
        if (t < 64) sT[64 * 64 + t] = f2bf(Kss[(size_t)g * KDIM + t]);
        for (int idx = t; idx < 960; idx += 256) sT[65 * 64 + idx] = 0;
    }

    // ---- S = Q·Kf^T : wave (rf = w&1, cfh = w>>1 -> cf {2cfh, 2cfh+1}) ----
    const int rf = w & 1;
    short8v qa[2];
#pragma unroll
    for (int ks = 0; ks < 2; ++ks)
        qa[ks] = *(const short8v*)&Qf[((size_t)((g * 2 + rh) * 4 + rf * 2 + ks)) * 512 + l * 8];
    {
        const int cfh = w >> 1;
        f32x4 accs[2];
#pragma unroll
        for (int ci = 0; ci < 2; ++ci) accs[ci] = (f32x4){0.f, 0.f, 0.f, 0.f};
#pragma unroll
        for (int ci = 0; ci < 2; ++ci) {
            const int cf = cfh * 2 + ci;
#pragma unroll
            for (int ks = 0; ks < 2; ++ks) {
                short8v kb = *(const short8v*)&Kff[((size_t)((g * 2 + (cf >> 1)) * 4 + (cf & 1) * 2 + ks)) * 512 + l * 8];
                accs[ci] = MFMA16(qa[ks], kb, accs[ci], 0, 0, 0);
            }
        }
#pragma unroll
        for (int ci = 0; ci < 2; ++ci)
#pragma unroll
            for (int q = 0; q < 4; ++q) {
                const int row = rf * 16 + lq * 4 + q;          // block-local 0..31
                const int col = (cfh * 2 + ci) * 16 + (l & 15); // chunk-local j
                const float sv = (col <= rh * 32 + row) ? accs[ci][q] : 0.f;
                pb[row * 64 + (col ^ ((row & 7) << 3))] = f2bf(sv);
            }
    }
    __syncthreads();

    // ---- num/den: wave (rf, mg = w>>1 -> mf {2mg, 2mg+1}) + own den ----
    const int mg = w >> 1;
    f32x4 an0 = (f32x4){0.f,0.f,0.f,0.f}, an1 = (f32x4){0.f,0.f,0.f,0.f};
    f32x4 ad = (f32x4){0.f,0.f,0.f,0.f};
    short8v onesf;
#pragma unroll
    for (int e = 0; e < 8; ++e) onesf[e] = ((l & 15) == 0) ? (short)0x3F80 : (short)0;
#pragma unroll
    for (int js = 0; js < 2; ++js) {
        const int prow = rf * 16 + (l & 15);
        const int pbase = js * 32 + ((l >> 4) & 3) * 8;
        short8v pa = *(const short8v*)&pb[prow * 64 + (pbase ^ ((prow & 7) << 3))];
        short8v v0 = *(const short8v*)&VT[((size_t)(g * 8 + (mg * 2 + 0) * 2 + js)) * 512 + l * 8];
        short8v v1 = *(const short8v*)&VT[((size_t)(g * 8 + (mg * 2 + 1) * 2 + js)) * 512 + l * 8];
        an0 = MFMA16(pa, v0, an0, 0, 0, 0);
        an1 = MFMA16(pa, v1, an1, 0, 0, 0);
        ad  = MFMA16(pa, onesf, ad, 0, 0, 0);
    }
#pragma unroll
    for (int ks = 0; ks < 2; ++ks) {
        const int base = ks * 32 + ((l >> 4) & 3) * 8;
        const int r0 = (mg * 2 + 0) * 16 + (l & 15);
        const int r1 = (mg * 2 + 1) * 16 + (l & 15);
        const int r4 = 64 + (l & 15);
        short8v s0 = *(const short8v*)&sT[r0 * 64 + (base ^ ((r0 & 7) << 3))];
        short8v s1 = *(const short8v*)&sT[r1 * 64 + (base ^ ((r1 & 7) << 3))];
        short8v s4 = *(const short8v*)&sT[r4 * 64 + (base ^ ((r4 & 7) << 3))];
        an0 = MFMA16(qa[ks], s0, an0, 0, 0, 0);
        an1 = MFMA16(qa[ks], s1, an1, 0, 0, 0);
        ad  = MFMA16(qa[ks], s4, ad, 0, 0, 0);
    }
    // ---- O = num/(den+1e-6) -> pb ----
#pragma unroll
    for (int q = 0; q < 4; ++q) {
        const float den = __shfl(ad[q], (l & 48));
        const float rinv = 1.f / (den + 1e-6f);
        const int row = rf * 16 + lq * 4 + q;
        const int c0 = (mg * 2 + 0) * 16 + (l & 15);
        const int c1 = (mg * 2 + 1) * 16 + (l & 15);
        pb[row * 64 + (c0 ^ ((row & 7) << 3))] = f2bf(an0[q] * rinv);
        pb[row * 64 + (c1 ^ ((row & 7) << 3))] = f2bf(an1[q] * rinv);
    }
    __syncthreads();

    // ---- out = O·Wo^T : wave w owns out cols w*256..+255 ----
    short8v oa[2][2];
#pragma unroll
    for (int rfi = 0; rfi < 2; ++rfi)
#pragma unroll
        for (int ks = 0; ks < 2; ++ks) {
            const int row = rfi * 16 + (l & 15);
            const int base = ks * 32 + ((l >> 4) & 3) * 8;
            oa[rfi][ks] = *(const short8v*)&pb[row * 64 + (base ^ ((row & 7) << 3))];
        }
    float* obw = ob[w];
#pragma unroll
    for (int rr = 0; rr < 4; ++rr) {
        f32x4 acco[2][4];
#pragma unroll
        for (int rfi = 0; rfi < 2; ++rfi)
#pragma unroll
            for (int ci = 0; ci < 4; ++ci) acco[rfi][ci] = (f32x4){0.f, 0.f, 0.f, 0.f};
#pragma unroll
        for (int ci = 0; ci < 4; ++ci) {
            const int cfg = w * 16 + rr * 4 + ci;
#pragma unroll
            for (int ks = 0; ks < 2; ++ks) {
                short8v wb = *(const short8v*)&Wof[((size_t)(cfg * 2 + ks)) * 512 + l * 8];
#pragma unroll
                for (int rfi = 0; rfi < 2; ++rfi)
                    acco[rfi][ci] = MFMA16(oa[rfi][ks], wb, acco[rfi][ci], 0, 0, 0);
            }
        }
#pragma unroll
        for (int rfi = 0; rfi < 2; ++rfi) {
#pragma unroll
            for (int ci = 0; ci < 4; ++ci)
#pragma unroll
                for (int q = 0; q < 4; ++q)
                    obw[(lq * 4 + q) * 68 + ci * 16 + (l & 15)] = acco[rfi][ci][q];
#pragma unroll
            for (int rg = 0; rg < 4; ++rg) {
                const int row = rg * 4 + lq;
                float4 vv = *(const float4*)&obw[row * 68 + (l & 15) * 4];
                *(float4*)&out[((size_t)(g * 64 + rh * 32 + rfi * 16 + row)) * DDIM
                               + w * 256 + rr * 64 + (l & 15) * 4] = vv;
            }
        }
    }
}

extern "C" void kernel_launch(void* const* d_in, const int* in_sizes, int n_in,
                              void* d_out, int out_size, void* d_ws, size_t ws_size,
                              hipStream_t stream)
{
    const float* x  = (const float*)d_in[0];
    const float* Wq = (const float*)d_in[1];
    const float* Wk = (const float*)d_in[2];
    const float* Wv = (const float*)d_in[3];
    const float* Wo = (const float*)d_in[4];
    float* out = (float*)d_out;

    float* ws   = (float*)d_ws;
    float* KVc  = ws;                                  // 256*4096 f32
    float* Sst  = KVc + (size_t)TCHUNK * 4096;         // 256*4096 f32
    float* Ksc  = Sst + (size_t)TCHUNK * 4096;         // 256*64 f32
    float* Kss  = Ksc + (size_t)TCHUNK * KDIM;         // 256*64 f32
    ushort* Whf = (ushort*)(Kss + (size_t)TCHUNK * KDIM);  // 192*1024
    ushort* Wof = Whf + (size_t)192 * DDIM;                // 64*1024
    ushort* Qf  = Wof + (size_t)64 * 1024;                 // 512*4*512
    ushort* Kff = Qf  + (size_t)512 * 4 * 512;
    ushort* VT  = Kff + (size_t)512 * 4 * 512;             // 256*8*512

    k_wconv<<<dim3(256), dim3(256), 0, stream>>>(Wq, Wk, Wv, Wo, Whf, Wof);
    k_proj<<<dim3(TCHUNK), dim3(512), 0, stream>>>(x, Whf, Qf, Kff, VT, KVc, Ksc);
    k_scan<<<dim3(BB * 65), dim3(64), 0, stream>>>(KVc, Ksc, Sst, Kss);
    k_intra<<<dim3(TCHUNK * 2), dim3(256), 0, stream>>>(Qf, Kff, VT, Sst, Kss, Wof, out);
}